// Round 2
// baseline (1030.593 us; speedup 1.0000x reference)
//
#include <hip/hip_runtime.h>
#include <hip/hip_bf16.h>
#include <math.h>

#define LL 1024

__device__ __forceinline__ float sigmoidf_(float x){ return 1.f/(1.f+__expf(-x)); }

// ---------------- im2col for k3 pad1: out[(b*L+l)*(3*Cin) + ci*3 + k] = x[b][ci][l-1+k]
__global__ __launch_bounds__(256) void im2col_k(
    const float* __restrict__ in, float* __restrict__ out, int Cin)
{
  int b = blockIdx.z;
  int ci = blockIdx.y;
  int l = blockIdx.x*256 + threadIdx.x;
  const float* p = in + ((size_t)b*Cin + ci)*LL;
  float xm1 = (l>0)? p[l-1] : 0.f;
  float x0  = p[l];
  float xp1 = (l<LL-1)? p[l+1] : 0.f;
  float* o = out + ((size_t)(b*LL + l)*3*Cin) + ci*3;
  o[0]=xm1; o[1]=x0; o[2]=xp1;
}

// ---------------- split-K reduce ----------------
// MODE 0: out[i] = s                      (i = n*M+m)
// MODE 1: out[(b*M+m)*LL+l] = s + bias[m]
// MODE 2: out[(b*M+m)*LL+l] = s + res[(b*M+m)*LL+l]
template<int MODE>
__global__ __launch_bounds__(256) void reduceK_k(
    const float* __restrict__ P, const float* __restrict__ bias,
    const float* __restrict__ res, float* __restrict__ out,
    int M, int N, int KS)
{
  int i = blockIdx.x*256 + threadIdx.x;
  if (i >= N*M) return;
  float s = 0.f;
  for (int k=0;k<KS;++k) s += P[(size_t)k*((size_t)N*M) + i];
  if (MODE==0){ out[i] = s; return; }
  int n = i / M, m = i - n*M;
  int b = n >> 10, l = n & 1023;
  size_t o = ((size_t)b*M + m)*LL + l;
  if (MODE==1) out[o] = s + bias[m];
  else         out[o] = s + res[o];
}

// ---------------- GroupNorm(32) + ReLU, in place ----------------
__global__ __launch_bounds__(256) void gn_relu_k(
    float* __restrict__ io, const float* __restrict__ g, const float* __restrict__ bt,
    int C, int Cg)
{
  int b = blockIdx.x >> 5;
  int grp = blockIdx.x & 31;
  int n = Cg * LL;
  float* p = io + ((size_t)b*C + (size_t)grp*Cg)*LL;
  int tid = threadIdx.x;
  float s=0.f, s2=0.f;
  for (int i=tid; i<n; i+=256){ float v=p[i]; s+=v; s2+=v*v; }
  __shared__ float red[10];
  #pragma unroll
  for (int off=32; off; off>>=1){ s+=__shfl_down(s,off); s2+=__shfl_down(s2,off); }
  if ((tid&63)==0){ red[tid>>6]=s; red[4+(tid>>6)]=s2; }
  __syncthreads();
  if (tid==0){
    float S=red[0]+red[1]+red[2]+red[3];
    float S2=red[4]+red[5]+red[6]+red[7];
    float mean = S/(float)n;
    float var = S2/(float)n - mean*mean;
    red[8]=mean; red[9]=rsqrtf(var+1e-5f);
  }
  __syncthreads();
  float mean=red[8], rstd=red[9];
  const float* gp = g + grp*Cg;
  const float* bp = bt + grp*Cg;
  for (int i=tid; i<n; i+=256){
    int co = i >> 10;
    float v = (p[i]-mean)*rstd*gp[co] + bp[co];
    p[i] = fmaxf(v, 0.f);
  }
}

// ---------------- LayerNorm over C=512 per (b,l); writes t[(b,l),c] ----------------
__global__ __launch_bounds__(64) void ln_k(
    const float* __restrict__ h, const float* __restrict__ g, const float* __restrict__ bt,
    float* __restrict__ tout)
{
  int bl = blockIdx.x;
  int b = bl >> 10, l = bl & 1023;
  int lane = threadIdx.x;
  const float* base = h + (size_t)b*512*LL + l;
  float v[8]; float s=0.f, s2=0.f;
  #pragma unroll
  for (int j=0;j<8;++j){ v[j] = base[(size_t)(lane + j*64)*LL]; s+=v[j]; s2+=v[j]*v[j]; }
  #pragma unroll
  for (int off=32; off; off>>=1){ s+=__shfl_xor(s,off); s2+=__shfl_xor(s2,off); }
  float mean = s*(1.f/512.f);
  float rstd = rsqrtf(s2*(1.f/512.f) - mean*mean + 1e-5f);
  float* o = tout + (size_t)bl*512;
  #pragma unroll
  for (int j=0;j<8;++j){ int c = lane + j*64; o[c] = (v[j]-mean)*rstd*g[c] + bt[c]; }
}

// ---------------- fp32 tiled GEMM: C[n][m] = sum_k B[n][k]*A[m][k] (+B2 on load) ----
// Split-K via gridDim.z (EPI=0 writes per-slice partials).
// EPI: 0 = P[z][n*M+m]; 1 = C[(b*M+m)*LL+l]; 2 = softplus(acc+bias[m]) at C[n*M+m]
template<int BM,int BN,int BK,int TM,int TN,int EPI>
__global__ __launch_bounds__(256) void gemm_nt(
    const float* __restrict__ A, const float* __restrict__ B1,
    const float* __restrict__ B2, const float* __restrict__ bias,
    float* __restrict__ C,
    int M, int N, int K, int lda, int ldb)
{
  __shared__ float As[BK][BM+4];
  __shared__ float Bs[BK][BN+4];
  int tid = threadIdx.x;
  int tx = tid & 15, ty = tid >> 4;
  int n0 = blockIdx.x * BN, m0 = blockIdx.y * BM;
  int Kc = K / gridDim.z;
  int kbeg = blockIdx.z * Kc;
  float acc[TM][TN];
  #pragma unroll
  for (int i=0;i<TM;++i)
    #pragma unroll
    for (int j=0;j<TN;++j) acc[i][j]=0.f;
  const int AR = tid / (BK/4);
  const int AK = (tid % (BK/4))*4;
  for (int k0=kbeg; k0<kbeg+Kc; k0+=BK) {
    float4 a4 = *(const float4*)(A + (size_t)(m0+AR)*lda + k0 + AK);
    float4 b4 = *(const float4*)(B1 + (size_t)(n0+AR)*ldb + k0 + AK);
    if (B2) {
      float4 c4 = *(const float4*)(B2 + (size_t)(n0+AR)*ldb + k0 + AK);
      b4.x+=c4.x; b4.y+=c4.y; b4.z+=c4.z; b4.w+=c4.w;
    }
    As[AK+0][AR]=a4.x; As[AK+1][AR]=a4.y; As[AK+2][AR]=a4.z; As[AK+3][AR]=a4.w;
    Bs[AK+0][AR]=b4.x; Bs[AK+1][AR]=b4.y; Bs[AK+2][AR]=b4.z; Bs[AK+3][AR]=b4.w;
    __syncthreads();
    #pragma unroll
    for (int kk=0;kk<BK;++kk){
      float av[TM], bv[TN];
      #pragma unroll
      for (int i=0;i<TM;i+=4) *(float4*)&av[i] = *(const float4*)&As[kk][tx*TM+i];
      #pragma unroll
      for (int j=0;j<TN;j+=4) *(float4*)&bv[j] = *(const float4*)&Bs[kk][ty*TN+j];
      #pragma unroll
      for (int i=0;i<TM;++i)
        #pragma unroll
        for (int j=0;j<TN;++j) acc[i][j] += av[i]*bv[j];
    }
    __syncthreads();
  }
  #pragma unroll
  for (int j=0;j<TN;++j){
    int n = n0 + ty*TN + j;
    int b = n >> 10, l = n & 1023;
    #pragma unroll
    for (int i=0;i<TM;++i){
      int m = m0 + tx*TM + i;
      float v = acc[i][j];
      if (EPI==0) C[(size_t)blockIdx.z*((size_t)N*M) + (size_t)n*M + m] = v;
      else if (EPI==1) C[((size_t)b*M + m)*LL + l] = v;
      else {
        float xv = v + bias[m];
        C[(size_t)n*M + m] = (xv > 20.f) ? xv : log1pf(expf(xv));
      }
    }
  }
}

// ---------------- causal depthwise conv k4 + SiLU, write transposed (b,l,d) ------
__global__ __launch_bounds__(256) void dwconv_k(
    const float* __restrict__ xz, const float* __restrict__ cw,
    const float* __restrict__ cb, float* __restrict__ outT, int rev)
{
  __shared__ float sx[64][73];
  int l0 = blockIdx.x * 64;
  int d0 = blockIdx.y * 64;
  int b = blockIdx.z;
  int tid = threadIdx.x;
  const float* base = xz + ((size_t)b*2048 + d0)*LL;
  for (int idx = tid; idx < 64*67; idx += 256) {
    int r = idx / 67, i = idx - r*67;
    int lp = l0 - 3 + i;
    float v = 0.f;
    if (lp >= 0) v = base[(size_t)r*LL + (rev ? (LL-1-lp) : lp)];
    sx[r][i] = v;
  }
  __syncthreads();
  int dof = tid & 63;
  int lq = tid >> 6;
  int d = d0 + dof;
  float4 w4 = *(const float4*)(cw + (size_t)d*4);
  float bv = cb[d];
  float* orow = outT + (size_t)b*LL*1024 + d;
  #pragma unroll
  for (int j=0;j<16;++j){
    int lr = lq + j*4;
    float acc = bv + w4.x*sx[dof][lr] + w4.y*sx[dof][lr+1]
                   + w4.z*sx[dof][lr+2] + w4.w*sx[dof][lr+3];
    orow[(size_t)(l0+lr)*1024] = acc * sigmoidf_(acc);
  }
}

// ---------------- selective scan, both dirs; 16 lanes per (b,d) channel ----------
__global__ __launch_bounds__(256) void scan_k(
    const float* __restrict__ u0, const float* __restrict__ u1,
    const float* __restrict__ de0, const float* __restrict__ de1,
    const float* __restrict__ xd0, const float* __restrict__ xd1,
    const float* __restrict__ al0, const float* __restrict__ al1,
    const float* __restrict__ dd0, const float* __restrict__ dd1,
    const float* __restrict__ xz, float* __restrict__ y0, float* __restrict__ y1)
{
  int dir = blockIdx.y;
  const float* uT = dir? u1:u0;  const float* de = dir? de1:de0;
  const float* xd = dir? xd1:xd0; const float* al = dir? al1:al0;
  const float* DD = dir? dd1:dd0; float* y = dir? y1:y0;
  int tid = threadIdx.x;
  int cl = tid>>4, s = tid&15;
  int c = blockIdx.x*16 + cl;
  int b = c>>10, d = c&1023;
  float A = -expf(al[d*16+s]);
  float Dd = DD[d];
  const float* zr = xz + ((size_t)b*2048 + 1024 + d)*LL;
  size_t nb = (size_t)b*1024;
  float h = 0.f;
  #pragma unroll 2
  for (int l=0;l<1024;++l){
    size_t n = nb + l;
    float dv = de[n*1024 + d];
    float uv = uT[n*1024 + d];
    float Bv = xd[n*64 + 32 + s];
    float Cv = xd[n*64 + 48 + s];
    h = __expf(dv*A)*h + dv*uv*Bv;
    float p = h*Cv;
    p += __shfl_xor(p,1,16); p += __shfl_xor(p,2,16);
    p += __shfl_xor(p,4,16); p += __shfl_xor(p,8,16);
    if (s==0){
      int lo = dir ? (1023-l) : l;
      float zv = zr[lo];
      y[(nb + lo)*1024 + d] = (p + uv*Dd) * (zv * sigmoidf_(zv));
    }
  }
}

extern "C" void kernel_launch(void* const* d_in, const int* in_sizes, int n_in,
                              void* d_out, int out_size, void* d_ws, size_t ws_size,
                              hipStream_t stream)
{
  const float* x   = (const float*)d_in[0];
  const float* c1w = (const float*)d_in[1];  const float* c1b = (const float*)d_in[2];
  const float* g1g = (const float*)d_in[3];  const float* g1b = (const float*)d_in[4];
  const float* c2w = (const float*)d_in[5];  const float* c2b = (const float*)d_in[6];
  const float* g2g = (const float*)d_in[7];  const float* g2b = (const float*)d_in[8];
  const float* c3w = (const float*)d_in[9];  const float* c3b = (const float*)d_in[10];
  const float* g3g = (const float*)d_in[11]; const float* g3b = (const float*)d_in[12];
  const float* lng = (const float*)d_in[13]; const float* lnb = (const float*)d_in[14];
  const float* ipw = (const float*)d_in[15]; const float* opw = (const float*)d_in[16];
  const float* cvw[2]  = {(const float*)d_in[17], (const float*)d_in[24]};
  const float* cvb[2]  = {(const float*)d_in[18], (const float*)d_in[25]};
  const float* xpw[2]  = {(const float*)d_in[19], (const float*)d_in[26]};
  const float* dtw[2]  = {(const float*)d_in[20], (const float*)d_in[27]};
  const float* dtb[2]  = {(const float*)d_in[21], (const float*)d_in[28]};
  const float* alog[2] = {(const float*)d_in[22], (const float*)d_in[29]};
  const float* Dp[2]   = {(const float*)d_in[23], (const float*)d_in[30]};

  float* ws = (float*)d_ws;
  float* h1 = ws;                      // 262144
  float* h2 = h1 + 262144;             // 524288
  float* h3 = h2 + 524288;             // 1048576 (residual)
  float* t  = h3 + 1048576;            // 1048576
  float* xzb = t + 1048576;            // 4194304
  float* arena = xzb + 4194304;        // 12845056 floats
  float* xcv[2]; xcv[0] = arena;           xcv[1] = xcv[0] + 2097152;
  float* xdb[2]; xdb[0] = xcv[1] + 2097152; xdb[1] = xdb[0] + 131072;
  float* dl[2];  dl[0]  = xdb[1] + 131072;  dl[1]  = dl[0] + 2097152;
  float* yy[2];  yy[0]  = dl[1] + 2097152;  yy[1]  = yy[0] + 2097152;
  // phase aliases (regions dead during their phase)
  float* icb   = arena;                // im2col buf (stem)      <= 4718592
  float* pstem = arena + 4718592;      // stem split-K partials  <= 2097152
  float* pxp   = yy[0];                // xp split-K partials    <= 1048576 (pre-scan)
  float* pout  = xzb;                  // out_proj partials      <= 2097152 (post-scan)
  float* out = (float*)d_out;

  // ---- CNN stem: im2col + split-K GEMM + bias-reduce + GN/ReLU ----
  im2col_k<<<dim3(4,768,2), 256, 0, stream>>>(x, icb, 768);
  gemm_nt<64,64,16,4,4,0><<<dim3(32,2,4), 256, 0, stream>>>(
      c1w, icb, nullptr, nullptr, pstem, 128, 2048, 2304, 2304, 2304);
  reduceK_k<1><<<1024, 256, 0, stream>>>(pstem, c1b, nullptr, h1, 128, 2048, 4);
  gn_relu_k<<<64, 256, 0, stream>>>(h1, g1g, g1b, 128, 4);

  im2col_k<<<dim3(4,128,2), 256, 0, stream>>>(h1, icb, 128);
  gemm_nt<64,64,16,4,4,0><<<dim3(32,4,2), 256, 0, stream>>>(
      c2w, icb, nullptr, nullptr, pstem, 256, 2048, 384, 384, 384);
  reduceK_k<1><<<2048, 256, 0, stream>>>(pstem, c2b, nullptr, h2, 256, 2048, 2);
  gn_relu_k<<<64, 256, 0, stream>>>(h2, g2g, g2b, 256, 8);

  im2col_k<<<dim3(4,256,2), 256, 0, stream>>>(h2, icb, 256);
  gemm_nt<64,64,16,4,4,0><<<dim3(32,8,2), 256, 0, stream>>>(
      c3w, icb, nullptr, nullptr, pstem, 512, 2048, 768, 768, 768);
  reduceK_k<1><<<4096, 256, 0, stream>>>(pstem, c3b, nullptr, h3, 512, 2048, 2);
  gn_relu_k<<<64, 256, 0, stream>>>(h3, g3g, g3b, 512, 16);

  // ---- LayerNorm -> t (B*L, 512) ----
  ln_k<<<2048, 64, 0, stream>>>(h3, lng, lnb, t);

  // ---- in_proj -> xz (B, 2048, L) ----
  gemm_nt<128,128,8,8,8,1><<<dim3(16,16), 256, 0, stream>>>(
      ipw, t, nullptr, nullptr, xzb, 2048, 2048, 512, 512, 512);

  // ---- per-direction conv/proj/delta ----
  for (int s2=0; s2<2; ++s2){
    dwconv_k<<<dim3(16,16,2), 256, 0, stream>>>(xzb, cvw[s2], cvb[s2], xcv[s2], s2);
    gemm_nt<64,64,16,4,4,0><<<dim3(32,1,8), 256, 0, stream>>>(
        xpw[s2], xcv[s2], nullptr, nullptr, pxp, 64, 2048, 1024, 1024, 1024);
    reduceK_k<0><<<512, 256, 0, stream>>>(pxp, nullptr, nullptr, xdb[s2], 64, 2048, 8);
    gemm_nt<64,64,16,4,4,2><<<dim3(32,16), 256, 0, stream>>>(
        dtw[s2], xdb[s2], nullptr, dtb[s2], dl[s2], 1024, 2048, 32, 32, 64);
  }

  // ---- selective scan, both directions ----
  scan_k<<<dim3(128,2), 256, 0, stream>>>(
      xcv[0], xcv[1], dl[0], dl[1], xdb[0], xdb[1],
      alog[0], alog[1], Dp[0], Dp[1], xzb, yy[0], yy[1]);

  // ---- out_proj (B operand = yf + yr) + residual ----
  gemm_nt<64,64,16,4,4,0><<<dim3(32,8,2), 256, 0, stream>>>(
      opw, yy[0], yy[1], nullptr, pout, 512, 2048, 1024, 1024, 1024);
  reduceK_k<2><<<4096, 256, 0, stream>>>(pout, nullptr, h3, out, 512, 2048, 2);
}

// Round 3
// 629.333 us; speedup vs baseline: 1.6376x; 1.6376x over previous
//
#include <hip/hip_runtime.h>
#include <hip/hip_bf16.h>
#include <math.h>

#define LL 1024
#define NC 8
#define CS 128

__device__ __forceinline__ float sigmoidf_(float x){ return 1.f/(1.f+__expf(-x)); }

// ---------------- im2col for k3 pad1: out[(b*L+l)*(3*Cin) + ci*3 + k] = x[b][ci][l-1+k]
__global__ __launch_bounds__(256) void im2col_k(
    const float* __restrict__ in, float* __restrict__ out, int Cin)
{
  int b = blockIdx.z;
  int ci = blockIdx.y;
  int l = blockIdx.x*256 + threadIdx.x;
  const float* p = in + ((size_t)b*Cin + ci)*LL;
  float xm1 = (l>0)? p[l-1] : 0.f;
  float x0  = p[l];
  float xp1 = (l<LL-1)? p[l+1] : 0.f;
  float* o = out + ((size_t)(b*LL + l)*3*Cin) + ci*3;
  o[0]=xm1; o[1]=x0; o[2]=xp1;
}

// ---------------- split-K reduce ----------------
// MODE 0: out[i] = s                      (i = n*M+m)
// MODE 1: out[(b*M+m)*LL+l] = s + bias[m]
// MODE 2: out[(b*M+m)*LL+l] = s + res[(b*M+m)*LL+l]
template<int MODE>
__global__ __launch_bounds__(256) void reduceK_k(
    const float* __restrict__ P, const float* __restrict__ bias,
    const float* __restrict__ res, float* __restrict__ out,
    int M, int N, int KS)
{
  int i = blockIdx.x*256 + threadIdx.x;
  if (i >= N*M) return;
  float s = 0.f;
  for (int k=0;k<KS;++k) s += P[(size_t)k*((size_t)N*M) + i];
  if (MODE==0){ out[i] = s; return; }
  int n = i / M, m = i - n*M;
  int b = n >> 10, l = n & 1023;
  size_t o = ((size_t)b*M + m)*LL + l;
  if (MODE==1) out[o] = s + bias[m];
  else         out[o] = s + res[o];
}

// ---------------- GroupNorm(32) + ReLU, in place ----------------
__global__ __launch_bounds__(256) void gn_relu_k(
    float* __restrict__ io, const float* __restrict__ g, const float* __restrict__ bt,
    int C, int Cg)
{
  int b = blockIdx.x >> 5;
  int grp = blockIdx.x & 31;
  int n = Cg * LL;
  float* p = io + ((size_t)b*C + (size_t)grp*Cg)*LL;
  int tid = threadIdx.x;
  float s=0.f, s2=0.f;
  for (int i=tid; i<n; i+=256){ float v=p[i]; s+=v; s2+=v*v; }
  __shared__ float red[10];
  #pragma unroll
  for (int off=32; off; off>>=1){ s+=__shfl_down(s,off); s2+=__shfl_down(s2,off); }
  if ((tid&63)==0){ red[tid>>6]=s; red[4+(tid>>6)]=s2; }
  __syncthreads();
  if (tid==0){
    float S=red[0]+red[1]+red[2]+red[3];
    float S2=red[4]+red[5]+red[6]+red[7];
    float mean = S/(float)n;
    float var = S2/(float)n - mean*mean;
    red[8]=mean; red[9]=rsqrtf(var+1e-5f);
  }
  __syncthreads();
  float mean=red[8], rstd=red[9];
  const float* gp = g + grp*Cg;
  const float* bp = bt + grp*Cg;
  for (int i=tid; i<n; i+=256){
    int co = i >> 10;
    float v = (p[i]-mean)*rstd*gp[co] + bp[co];
    p[i] = fmaxf(v, 0.f);
  }
}

// ---------------- LayerNorm over C=512 per (b,l); writes t[(b,l),c] ----------------
__global__ __launch_bounds__(64) void ln_k(
    const float* __restrict__ h, const float* __restrict__ g, const float* __restrict__ bt,
    float* __restrict__ tout)
{
  int bl = blockIdx.x;
  int b = bl >> 10, l = bl & 1023;
  int lane = threadIdx.x;
  const float* base = h + (size_t)b*512*LL + l;
  float v[8]; float s=0.f, s2=0.f;
  #pragma unroll
  for (int j=0;j<8;++j){ v[j] = base[(size_t)(lane + j*64)*LL]; s+=v[j]; s2+=v[j]*v[j]; }
  #pragma unroll
  for (int off=32; off; off>>=1){ s+=__shfl_xor(s,off); s2+=__shfl_xor(s2,off); }
  float mean = s*(1.f/512.f);
  float rstd = rsqrtf(s2*(1.f/512.f) - mean*mean + 1e-5f);
  float* o = tout + (size_t)bl*512;
  #pragma unroll
  for (int j=0;j<8;++j){ int c = lane + j*64; o[c] = (v[j]-mean)*rstd*g[c] + bt[c]; }
}

// ---------------- fp32 tiled GEMM: C[n][m] = sum_k B[n][k]*A[m][k] (+B2 on load) ----
// Split-K via gridDim.z (EPI=0 writes per-slice partials).
// EPI: 0 = P[z][n*M+m]; 1 = C[(b*M+m)*LL+l]; 2 = softplus(acc+bias[m]) at C[n*M+m]
template<int BM,int BN,int BK,int TM,int TN,int EPI>
__global__ __launch_bounds__(256) void gemm_nt(
    const float* __restrict__ A, const float* __restrict__ B1,
    const float* __restrict__ B2, const float* __restrict__ bias,
    float* __restrict__ C,
    int M, int N, int K, int lda, int ldb)
{
  __shared__ float As[BK][BM+4];
  __shared__ float Bs[BK][BN+4];
  int tid = threadIdx.x;
  int tx = tid & 15, ty = tid >> 4;
  int n0 = blockIdx.x * BN, m0 = blockIdx.y * BM;
  int Kc = K / gridDim.z;
  int kbeg = blockIdx.z * Kc;
  float acc[TM][TN];
  #pragma unroll
  for (int i=0;i<TM;++i)
    #pragma unroll
    for (int j=0;j<TN;++j) acc[i][j]=0.f;
  const int AR = tid / (BK/4);
  const int AK = (tid % (BK/4))*4;
  for (int k0=kbeg; k0<kbeg+Kc; k0+=BK) {
    float4 a4 = *(const float4*)(A + (size_t)(m0+AR)*lda + k0 + AK);
    float4 b4 = *(const float4*)(B1 + (size_t)(n0+AR)*ldb + k0 + AK);
    if (B2) {
      float4 c4 = *(const float4*)(B2 + (size_t)(n0+AR)*ldb + k0 + AK);
      b4.x+=c4.x; b4.y+=c4.y; b4.z+=c4.z; b4.w+=c4.w;
    }
    As[AK+0][AR]=a4.x; As[AK+1][AR]=a4.y; As[AK+2][AR]=a4.z; As[AK+3][AR]=a4.w;
    Bs[AK+0][AR]=b4.x; Bs[AK+1][AR]=b4.y; Bs[AK+2][AR]=b4.z; Bs[AK+3][AR]=b4.w;
    __syncthreads();
    #pragma unroll
    for (int kk=0;kk<BK;++kk){
      float av[TM], bv[TN];
      #pragma unroll
      for (int i=0;i<TM;i+=4) *(float4*)&av[i] = *(const float4*)&As[kk][tx*TM+i];
      #pragma unroll
      for (int j=0;j<TN;j+=4) *(float4*)&bv[j] = *(const float4*)&Bs[kk][ty*TN+j];
      #pragma unroll
      for (int i=0;i<TM;++i)
        #pragma unroll
        for (int j=0;j<TN;++j) acc[i][j] += av[i]*bv[j];
    }
    __syncthreads();
  }
  #pragma unroll
  for (int j=0;j<TN;++j){
    int n = n0 + ty*TN + j;
    int b = n >> 10, l = n & 1023;
    #pragma unroll
    for (int i=0;i<TM;++i){
      int m = m0 + tx*TM + i;
      float v = acc[i][j];
      if (EPI==0) C[(size_t)blockIdx.z*((size_t)N*M) + (size_t)n*M + m] = v;
      else if (EPI==1) C[((size_t)b*M + m)*LL + l] = v;
      else {
        float xv = v + bias[m];
        C[(size_t)n*M + m] = (xv > 20.f) ? xv : log1pf(expf(xv));
      }
    }
  }
}

// ---------------- causal depthwise conv k4 + SiLU, write transposed (b,l,d) ------
__global__ __launch_bounds__(256) void dwconv_k(
    const float* __restrict__ xz, const float* __restrict__ cw,
    const float* __restrict__ cb, float* __restrict__ outT, int rev)
{
  __shared__ float sx[64][73];
  int l0 = blockIdx.x * 64;
  int d0 = blockIdx.y * 64;
  int b = blockIdx.z;
  int tid = threadIdx.x;
  const float* base = xz + ((size_t)b*2048 + d0)*LL;
  for (int idx = tid; idx < 64*67; idx += 256) {
    int r = idx / 67, i = idx - r*67;
    int lp = l0 - 3 + i;
    float v = 0.f;
    if (lp >= 0) v = base[(size_t)r*LL + (rev ? (LL-1-lp) : lp)];
    sx[r][i] = v;
  }
  __syncthreads();
  int dof = tid & 63;
  int lq = tid >> 6;
  int d = d0 + dof;
  float4 w4 = *(const float4*)(cw + (size_t)d*4);
  float bv = cb[d];
  float* orow = outT + (size_t)b*LL*1024 + d;
  #pragma unroll
  for (int j=0;j<16;++j){
    int lr = lq + j*4;
    float acc = bv + w4.x*sx[dof][lr] + w4.y*sx[dof][lr+1]
                   + w4.z*sx[dof][lr+2] + w4.w*sx[dof][lr+3];
    orow[(size_t)(l0+lr)*1024] = acc * sigmoidf_(acc);
  }
}

// ================= chunked selective scan =================
// Sequences: seq = (dir*2048 + b*1024 + d)*16 + s, 65536 total, length L=1024,
// split into NC=8 chunks of CS=128.
// pass1: from h=0 within chunk -> P = prod(a), S = partial state.
// pass2: scan over chunks -> Hbuf[chunk] = state at chunk start.
// pass3: recompute within chunk from Hbuf, emit gated y.

__global__ __launch_bounds__(256) void scan1_k(
    const float* __restrict__ de0, const float* __restrict__ de1,
    const float* __restrict__ u0, const float* __restrict__ u1,
    const float* __restrict__ xd0, const float* __restrict__ xd1,
    const float* __restrict__ al0, const float* __restrict__ al1,
    float* __restrict__ Pbuf, float* __restrict__ Sbuf)
{
  int dir = blockIdx.z;
  const float* de = dir? de1:de0;
  const float* uT = dir? u1:u0;
  const float* xd = dir? xd1:xd0;
  const float* al = dir? al1:al0;
  int tid = threadIdx.x;
  int cl = tid>>4, s = tid&15;
  int c = blockIdx.x*16 + cl;         // b*1024 + d
  int d = c & 1023;
  int chunk = blockIdx.y;
  float A = -expf(al[d*16+s]);
  size_t nb = (size_t)(c>>10)*1024;
  float h = 0.f, P = 1.f;
  int l0 = chunk*CS;
  #pragma unroll 4
  for (int l=l0; l<l0+CS; ++l){
    size_t n = nb + l;
    float dv = de[n*1024 + d];
    float uv = uT[n*1024 + d];
    float Bv = xd[n*64 + 32 + s];
    float a = __expf(dv*A);
    h = a*h + dv*uv*Bv;
    P *= a;
  }
  int seq = ((dir<<11) + c)*16 + s;
  Pbuf[(size_t)chunk*65536 + seq] = P;
  Sbuf[(size_t)chunk*65536 + seq] = h;
}

__global__ __launch_bounds__(256) void scan2_k(
    const float* __restrict__ Pbuf, const float* __restrict__ Sbuf,
    float* __restrict__ Hbuf)
{
  int seq = blockIdx.x*256 + threadIdx.x;
  float H = 0.f;
  #pragma unroll
  for (int cch=0; cch<NC; ++cch){
    Hbuf[(size_t)cch*65536 + seq] = H;
    H = Pbuf[(size_t)cch*65536 + seq]*H + Sbuf[(size_t)cch*65536 + seq];
  }
}

__global__ __launch_bounds__(256) void scan3_k(
    const float* __restrict__ de0, const float* __restrict__ de1,
    const float* __restrict__ u0, const float* __restrict__ u1,
    const float* __restrict__ xd0, const float* __restrict__ xd1,
    const float* __restrict__ al0, const float* __restrict__ al1,
    const float* __restrict__ dd0, const float* __restrict__ dd1,
    const float* __restrict__ xz, const float* __restrict__ Hbuf,
    float* __restrict__ y0, float* __restrict__ y1)
{
  int dir = blockIdx.z;
  const float* de = dir? de1:de0;
  const float* uT = dir? u1:u0;
  const float* xd = dir? xd1:xd0;
  const float* al = dir? al1:al0;
  const float* DD = dir? dd1:dd0;
  float* y = dir? y1:y0;
  int tid = threadIdx.x;
  int cl = tid>>4, s = tid&15;
  int c = blockIdx.x*16 + cl;
  int b = c>>10, d = c & 1023;
  int chunk = blockIdx.y;
  float A = -expf(al[d*16+s]);
  float Dd = DD[d];
  const float* zr = xz + ((size_t)b*2048 + 1024 + d)*LL;
  size_t nb = (size_t)b*1024;
  int seq = ((dir<<11) + c)*16 + s;
  float h = Hbuf[(size_t)chunk*65536 + seq];
  int l0 = chunk*CS;
  #pragma unroll 2
  for (int l=l0; l<l0+CS; ++l){
    size_t n = nb + l;
    float dv = de[n*1024 + d];
    float uv = uT[n*1024 + d];
    float Bv = xd[n*64 + 32 + s];
    float Cv = xd[n*64 + 48 + s];
    h = __expf(dv*A)*h + dv*uv*Bv;
    float p = h*Cv;
    p += __shfl_xor(p,1,16); p += __shfl_xor(p,2,16);
    p += __shfl_xor(p,4,16); p += __shfl_xor(p,8,16);
    if (s==0){
      int lo = dir ? (1023-l) : l;
      float zv = zr[lo];
      y[(nb + lo)*1024 + d] = (p + uv*Dd) * (zv * sigmoidf_(zv));
    }
  }
}

extern "C" void kernel_launch(void* const* d_in, const int* in_sizes, int n_in,
                              void* d_out, int out_size, void* d_ws, size_t ws_size,
                              hipStream_t stream)
{
  const float* x   = (const float*)d_in[0];
  const float* c1w = (const float*)d_in[1];  const float* c1b = (const float*)d_in[2];
  const float* g1g = (const float*)d_in[3];  const float* g1b = (const float*)d_in[4];
  const float* c2w = (const float*)d_in[5];  const float* c2b = (const float*)d_in[6];
  const float* g2g = (const float*)d_in[7];  const float* g2b = (const float*)d_in[8];
  const float* c3w = (const float*)d_in[9];  const float* c3b = (const float*)d_in[10];
  const float* g3g = (const float*)d_in[11]; const float* g3b = (const float*)d_in[12];
  const float* lng = (const float*)d_in[13]; const float* lnb = (const float*)d_in[14];
  const float* ipw = (const float*)d_in[15]; const float* opw = (const float*)d_in[16];
  const float* cvw[2]  = {(const float*)d_in[17], (const float*)d_in[24]};
  const float* cvb[2]  = {(const float*)d_in[18], (const float*)d_in[25]};
  const float* xpw[2]  = {(const float*)d_in[19], (const float*)d_in[26]};
  const float* dtw[2]  = {(const float*)d_in[20], (const float*)d_in[27]};
  const float* dtb[2]  = {(const float*)d_in[21], (const float*)d_in[28]};
  const float* alog[2] = {(const float*)d_in[22], (const float*)d_in[29]};
  const float* Dp[2]   = {(const float*)d_in[23], (const float*)d_in[30]};

  float* ws = (float*)d_ws;
  float* h1 = ws;                      // 262144
  float* h2 = h1 + 262144;             // 524288
  float* h3 = h2 + 524288;             // 1048576 (residual)
  float* t  = h3 + 1048576;            // 1048576
  float* xzb = t + 1048576;            // 4194304
  float* arena = xzb + 4194304;        // 12845056 floats
  float* xcv[2]; xcv[0] = arena;           xcv[1] = xcv[0] + 2097152;
  float* xdb[2]; xdb[0] = xcv[1] + 2097152; xdb[1] = xdb[0] + 131072;
  float* dl[2];  dl[0]  = xdb[1] + 131072;  dl[1]  = dl[0] + 2097152;
  float* yy[2];  yy[0]  = dl[1] + 2097152;  yy[1]  = yy[0] + 2097152;
  // phase aliases (regions dead during their phase)
  float* icb   = arena;                // im2col buf (stem)      <= 4718592
  float* pstem = arena + 4718592;      // stem split-K partials  <= 2097152
  float* pxp   = yy[0];                // xp split-K partials    <= 1048576 (pre-scan)
  float* pout  = xzb;                  // out_proj partials      <= 2097152 (post-scan)
  float* Pb = t;                       // scan chunk products    524288 (t dead post-in_proj)
  float* Sb = t + 524288;              // scan chunk partials    524288
  float* Hb = h2;                      // scan chunk-start state 524288 (h2 dead post-stem)
  float* out = (float*)d_out;

  // ---- CNN stem: im2col + split-K GEMM + bias-reduce + GN/ReLU ----
  im2col_k<<<dim3(4,768,2), 256, 0, stream>>>(x, icb, 768);
  gemm_nt<64,64,16,4,4,0><<<dim3(32,2,4), 256, 0, stream>>>(
      c1w, icb, nullptr, nullptr, pstem, 128, 2048, 2304, 2304, 2304);
  reduceK_k<1><<<1024, 256, 0, stream>>>(pstem, c1b, nullptr, h1, 128, 2048, 4);
  gn_relu_k<<<64, 256, 0, stream>>>(h1, g1g, g1b, 128, 4);

  im2col_k<<<dim3(4,128,2), 256, 0, stream>>>(h1, icb, 128);
  gemm_nt<64,64,16,4,4,0><<<dim3(32,4,2), 256, 0, stream>>>(
      c2w, icb, nullptr, nullptr, pstem, 256, 2048, 384, 384, 384);
  reduceK_k<1><<<2048, 256, 0, stream>>>(pstem, c2b, nullptr, h2, 256, 2048, 2);
  gn_relu_k<<<64, 256, 0, stream>>>(h2, g2g, g2b, 256, 8);

  im2col_k<<<dim3(4,256,2), 256, 0, stream>>>(h2, icb, 256);
  gemm_nt<64,64,16,4,4,0><<<dim3(32,8,2), 256, 0, stream>>>(
      c3w, icb, nullptr, nullptr, pstem, 512, 2048, 768, 768, 768);
  reduceK_k<1><<<4096, 256, 0, stream>>>(pstem, c3b, nullptr, h3, 512, 2048, 2);
  gn_relu_k<<<64, 256, 0, stream>>>(h3, g3g, g3b, 512, 16);

  // ---- LayerNorm -> t (B*L, 512) ----
  ln_k<<<2048, 64, 0, stream>>>(h3, lng, lnb, t);

  // ---- in_proj -> xz (B, 2048, L) ----
  gemm_nt<128,128,8,8,8,1><<<dim3(16,16), 256, 0, stream>>>(
      ipw, t, nullptr, nullptr, xzb, 2048, 2048, 512, 512, 512);

  // ---- per-direction conv/proj/delta ----
  for (int s2=0; s2<2; ++s2){
    dwconv_k<<<dim3(16,16,2), 256, 0, stream>>>(xzb, cvw[s2], cvb[s2], xcv[s2], s2);
    gemm_nt<64,64,16,4,4,0><<<dim3(32,1,8), 256, 0, stream>>>(
        xpw[s2], xcv[s2], nullptr, nullptr, pxp, 64, 2048, 1024, 1024, 1024);
    reduceK_k<0><<<512, 256, 0, stream>>>(pxp, nullptr, nullptr, xdb[s2], 64, 2048, 8);
    gemm_nt<64,64,16,4,4,2><<<dim3(32,16), 256, 0, stream>>>(
        dtw[s2], xdb[s2], nullptr, dtb[s2], dl[s2], 1024, 2048, 32, 32, 64);
  }

  // ---- chunked selective scan, both directions ----
  scan1_k<<<dim3(128,NC,2), 256, 0, stream>>>(
      dl[0], dl[1], xcv[0], xcv[1], xdb[0], xdb[1], alog[0], alog[1], Pb, Sb);
  scan2_k<<<256, 256, 0, stream>>>(Pb, Sb, Hb);
  scan3_k<<<dim3(128,NC,2), 256, 0, stream>>>(
      dl[0], dl[1], xcv[0], xcv[1], xdb[0], xdb[1], alog[0], alog[1],
      Dp[0], Dp[1], xzb, Hb, yy[0], yy[1]);

  // ---- out_proj (B operand = yf + yr) + residual ----
  gemm_nt<64,64,16,4,4,0><<<dim3(32,8,2), 256, 0, stream>>>(
      opw, yy[0], yy[1], nullptr, pout, 512, 2048, 1024, 1024, 1024);
  reduceK_k<2><<<4096, 256, 0, stream>>>(pout, nullptr, h3, out, 512, 2048, 2);
}

// Round 7
// 542.235 us; speedup vs baseline: 1.9006x; 1.1606x over previous
//
#include <hip/hip_runtime.h>
#include <hip/hip_bf16.h>
#include <math.h>

#define LL 1024
#define NC 16
#define CS 64

typedef __attribute__((ext_vector_type(8))) short short8_t;
typedef __attribute__((ext_vector_type(4))) float f32x4;

__device__ __forceinline__ float sigmoidf_(float x){ return 1.f/(1.f+__expf(-x)); }
__device__ __forceinline__ unsigned short f2bu(float x){
  unsigned int u = __float_as_uint(x);
  unsigned int r = (u + 0x7fffu + ((u>>16)&1u)) >> 16;
  return (unsigned short)r;
}
__device__ __forceinline__ float bu2f(unsigned short u){
  return __uint_as_float(((unsigned int)u)<<16);
}

// ---------------- GroupNorm(32) + ReLU, in place ----------------
__global__ __launch_bounds__(256) void gn_relu_k(
    float* __restrict__ io, const float* __restrict__ g, const float* __restrict__ bt,
    int C, int Cg)
{
  int b = blockIdx.x >> 5;
  int grp = blockIdx.x & 31;
  int n = Cg * LL;
  float* p = io + ((size_t)b*C + (size_t)grp*Cg)*LL;
  int tid = threadIdx.x;
  float s=0.f, s2=0.f;
  for (int i=tid; i<n; i+=256){ float v=p[i]; s+=v; s2+=v*v; }
  __shared__ float red[10];
  #pragma unroll
  for (int off=32; off; off>>=1){ s+=__shfl_down(s,off); s2+=__shfl_down(s2,off); }
  if ((tid&63)==0){ red[tid>>6]=s; red[4+(tid>>6)]=s2; }
  __syncthreads();
  if (tid==0){
    float S=red[0]+red[1]+red[2]+red[3];
    float S2=red[4]+red[5]+red[6]+red[7];
    float mean = S/(float)n;
    float var = S2/(float)n - mean*mean;
    red[8]=mean; red[9]=rsqrtf(var+1e-5f);
  }
  __syncthreads();
  float mean=red[8], rstd=red[9];
  const float* gp = g + grp*Cg;
  const float* bp = bt + grp*Cg;
  for (int i=tid; i<n; i+=256){
    int co = i >> 10;
    float v = (p[i]-mean)*rstd*gp[co] + bp[co];
    p[i] = fmaxf(v, 0.f);
  }
}

// ---------------- LayerNorm over C=512 per (b,l) ----------------
__global__ __launch_bounds__(64) void ln_k(
    const float* __restrict__ h, const float* __restrict__ g, const float* __restrict__ bt,
    float* __restrict__ tout)
{
  int bl = blockIdx.x;
  int b = bl >> 10, l = bl & 1023;
  int lane = threadIdx.x;
  const float* base = h + (size_t)b*512*LL + l;
  float v[8]; float s=0.f, s2=0.f;
  #pragma unroll
  for (int j=0;j<8;++j){ v[j] = base[(size_t)(lane + j*64)*LL]; s+=v[j]; s2+=v[j]*v[j]; }
  #pragma unroll
  for (int off=32; off; off>>=1){ s+=__shfl_xor(s,off); s2+=__shfl_xor(s2,off); }
  float mean = s*(1.f/512.f);
  float rstd = rsqrtf(s2*(1.f/512.f) - mean*mean + 1e-5f);
  float* o = tout + (size_t)bl*512;
  #pragma unroll
  for (int j=0;j<8;++j){ int c = lane + j*64; o[c] = (v[j]-mean)*rstd*g[c] + bt[c]; }
}

// ---------------- split-K reduce ----------------
// MODE 0: out[i]=s ; MODE 1: out[(b*M+m)*LL+l]=s+bias[m] ; MODE 2: +res
template<int MODE>
__global__ __launch_bounds__(256) void reduceK_k(
    const float* __restrict__ P, const float* __restrict__ bias,
    const float* __restrict__ res, float* __restrict__ out,
    int M, int N, int KS)
{
  int i = blockIdx.x*256 + threadIdx.x;
  if (i >= N*M) return;
  float s = 0.f;
  for (int k=0;k<KS;++k) s += P[(size_t)k*((size_t)N*M) + i];
  if (MODE==0){ out[i] = s; return; }
  int n = i / M, m = i - n*M;
  int b = n >> 10, l = n & 1023;
  size_t o = ((size_t)b*M + m)*LL + l;
  if (MODE==1) out[o] = s + bias[m];
  else         out[o] = s + res[o];
}

// -------- stem B': transpose + split3, k = tap*Cin + ci, pattern [hi|hi|lo] ------
__global__ __launch_bounds__(256) void ts_split3_k(
    const float* __restrict__ src, unsigned short* __restrict__ dst, int Cin)
{
  __shared__ float sx[32][35];
  int b = blockIdx.z;
  int l0 = blockIdx.x*32, ci0 = blockIdx.y*32;
  int tid = threadIdx.x;
  const float* sb = src + ((size_t)b*Cin + ci0)*LL;
  for (int idx = tid; idx < 32*34; idx += 256){
    int r = idx / 34, c = idx - r*34;
    int lp = l0 - 1 + c;
    sx[r][c] = (lp >= 0 && lp < LL) ? sb[(size_t)r*LL + lp] : 0.f;
  }
  __syncthreads();
  int K = 3*Cin, K3 = 9*Cin;
  int lr = tid >> 5, cl = tid & 31;
  #pragma unroll
  for (int p=0;p<4;++p){
    int l = lr + p*8;
    unsigned short* drow = dst + (size_t)(b*LL + l0 + l)*K3;
    #pragma unroll
    for (int tap=0; tap<3; ++tap){
      float v = sx[cl][l + tap];
      unsigned short hi = f2bu(v);
      unsigned short lo = f2bu(v - bu2f(hi));
      int kk = tap*Cin + ci0 + cl;
      drow[kk] = hi; drow[K + kk] = hi; drow[2*K + kk] = lo;
    }
  }
}

// -------- conv weights A': [Cout][3K] tap-major, pattern [hi|lo|hi] ------
__global__ __launch_bounds__(256) void wsplit3_conv_k(
    const float* __restrict__ w, unsigned short* __restrict__ dst, int Cout, int Cin)
{
  int i = blockIdx.x*256 + threadIdx.x;
  if (i >= Cout*Cin) return;
  int co = i / Cin, ci = i - co*Cin;
  int K = 3*Cin, K3 = 9*Cin;
  unsigned short* drow = dst + (size_t)co*K3;
  #pragma unroll
  for (int tap=0; tap<3; ++tap){
    float v = w[(size_t)(co*Cin + ci)*3 + tap];
    unsigned short hi = f2bu(v);
    unsigned short lo = f2bu(v - bu2f(hi));
    int kk = tap*Cin + ci;
    drow[kk] = hi; drow[K + kk] = lo; drow[2*K + kk] = hi;
  }
}

// -------- row-major split3: PAT 0 = A-side [hi|lo|hi], PAT 1 = B-side [hi|hi|lo]
template<int PAT>
__global__ __launch_bounds__(256) void split3_k(
    const float* __restrict__ src, unsigned short* __restrict__ dst,
    int R, int K, int ld)
{
  int i = blockIdx.x*256 + threadIdx.x;
  int kq = K >> 2;
  if (i >= R*kq) return;
  int r = i / kq, k4 = (i - r*kq)*4;
  float4 v = *(const float4*)&src[(size_t)r*ld + k4];
  float vv[4] = {v.x, v.y, v.z, v.w};
  unsigned short hi[4], lo[4];
  #pragma unroll
  for (int j=0;j<4;++j){ hi[j]=f2bu(vv[j]); lo[j]=f2bu(vv[j]-bu2f(hi[j])); }
  unsigned short* d0 = dst + (size_t)r*3*K + k4;
  ushort4 h4 = make_ushort4(hi[0],hi[1],hi[2],hi[3]);
  ushort4 l4 = make_ushort4(lo[0],lo[1],lo[2],lo[3]);
  *(ushort4*)d0 = h4;
  *(ushort4*)(d0 + K)   = (PAT==0) ? l4 : h4;
  *(ushort4*)(d0 + 2*K) = (PAT==0) ? h4 : l4;
}

// -------- plain hi split (bf16 cast), cols [k0, k0+K) --------
__global__ __launch_bounds__(256) void split1_k(
    const float* __restrict__ src, unsigned short* __restrict__ dst,
    int R, int K, int ld, int k0)
{
  int i = blockIdx.x*256 + threadIdx.x;
  int kq = K >> 2;
  if (i >= R*kq) return;
  int r = i / kq, k4 = (i - r*kq)*4;
  float4 v = *(const float4*)&src[(size_t)r*ld + k0 + k4];
  *(ushort4*)(dst + (size_t)r*K + k4) =
      make_ushort4(f2bu(v.x), f2bu(v.y), f2bu(v.z), f2bu(v.w));
}

// -------- out-proj B: hi((y0+y1)*silu(z)), z transposed from xz --------
__global__ __launch_bounds__(256) void gated_split_k(
    const float* __restrict__ y0, const float* __restrict__ y1,
    const float* __restrict__ xz, unsigned short* __restrict__ dst)
{
  __shared__ float sz[32][33];
  int b = blockIdx.z;
  int l0 = blockIdx.x*32, d0 = blockIdx.y*32;
  int tid = threadIdx.x;
  const float* zb = xz + ((size_t)b*2048 + 1024 + d0)*LL + l0;
  for (int idx = tid; idx < 1024; idx += 256){
    int r = idx >> 5, c = idx & 31;
    sz[r][c] = zb[(size_t)r*LL + c];
  }
  __syncthreads();
  int lr = tid >> 5, dd = tid & 31;
  #pragma unroll
  for (int p=0;p<4;++p){
    int l = lr + p*8;
    size_t n = (size_t)b*LL + l0 + l;
    float zv = sz[dd][l];
    float y = y0[n*1024 + d0 + dd] + y1[n*1024 + d0 + dd];
    dst[n*1024 + d0 + dd] = f2bu(y * (zv * sigmoidf_(zv)));
  }
}

// ---------------- bf16 MFMA GEMM: C[n][m] = sum_k' B[n][k'] * A[m][k'] ----------
// A [M][K3], B [N][K3] bf16 row-major. 4 waves (2x2), wave tile (BM/2)x32.
// EPI 0: fp32 partials P[z][n*M+m]; EPI 1: C[(b*M+m)*LL+l]; EPI 2: bf16 softplus dl
template<int BM, int EPI>
__global__ __launch_bounds__(256) void gemm_bf3(
    const unsigned short* __restrict__ A, const unsigned short* __restrict__ B,
    const float* __restrict__ bias, void* __restrict__ Cv,
    int M, int N, int K3)
{
  constexpr int BN = 64;
  constexpr int AIT = (BM*4)/256;
  constexpr int FM = BM/32;
  __shared__ __align__(16) char smem[(BM+BN)*80];
  char* As = smem;
  char* Bs = smem + BM*80;
  int tid = threadIdx.x;
  int n0 = blockIdx.x*BN, m0 = blockIdx.y*BM;
  int kper = K3 / gridDim.z;
  int kbeg = blockIdx.z * kper;
  int w = tid >> 6, lane = tid & 63;
  int wm = w & 1, wn = w >> 1;
  f32x4 acc[FM][2];
  #pragma unroll
  for (int i=0;i<FM;++i){ acc[i][0] = (f32x4){0,0,0,0}; acc[i][1] = (f32x4){0,0,0,0}; }

  uint4 areg[AIT]; uint4 breg;
  auto load_stage = [&](int k){
    #pragma unroll
    for (int i=0;i<AIT;++i){
      int idx = tid + i*256;
      areg[i] = *(const uint4*)&A[(size_t)(m0 + (idx>>2))*K3 + k + (idx&3)*8];
    }
    breg = *(const uint4*)&B[(size_t)(n0 + (tid>>2))*K3 + k + (tid&3)*8];
  };
  load_stage(kbeg);
  for (int k = kbeg; k < kbeg + kper; k += 32){
    __syncthreads();
    #pragma unroll
    for (int i=0;i<AIT;++i){
      int idx = tid + i*256;
      *(uint4*)&As[(idx>>2)*80 + (idx&3)*16] = areg[i];
    }
    *(uint4*)&Bs[(tid>>2)*80 + (tid&3)*16] = breg;
    __syncthreads();
    if (k + 32 < kbeg + kper) load_stage(k + 32);
    int g16 = (lane>>4)*16, r16 = lane&15;
    short8_t bf0 = *(short8_t*)&Bs[(wn*32 + r16)*80 + g16];
    short8_t bf1 = *(short8_t*)&Bs[(wn*32 + 16 + r16)*80 + g16];
    #pragma unroll
    for (int i2=0;i2<FM;++i2){
      short8_t af = *(short8_t*)&As[(wm*(BM/2) + i2*16 + r16)*80 + g16];
      acc[i2][0] = __builtin_amdgcn_mfma_f32_16x16x32_bf16(af, bf0, acc[i2][0], 0,0,0);
      acc[i2][1] = __builtin_amdgcn_mfma_f32_16x16x32_bf16(af, bf1, acc[i2][1], 0,0,0);
    }
  }
  #pragma unroll
  for (int i2=0;i2<FM;++i2){
    #pragma unroll
    for (int j=0;j<2;++j){
      #pragma unroll
      for (int r=0;r<4;++r){
        int m = m0 + wm*(BM/2) + i2*16 + ((lane>>4)*4 + r);
        int n = n0 + wn*32 + j*16 + (lane&15);
        float v = acc[i2][j][r];
        if (EPI==0){
          ((float*)Cv)[(size_t)blockIdx.z*((size_t)N*M) + (size_t)n*M + m] = v;
        } else if (EPI==1){
          int b = n>>10, l = n&1023;
          ((float*)Cv)[((size_t)b*M + m)*LL + l] = v;
        } else {
          float xv = v + bias[m];
          float sp = (xv > 20.f) ? xv : log1pf(__expf(xv));
          ((unsigned short*)Cv)[(size_t)n*M + m] = f2bu(sp);
        }
      }
    }
  }
}

// -------- causal depthwise conv k4 + SiLU, bf16 transposed out (b,l,d) ------
__global__ __launch_bounds__(256) void dwconv_k(
    const float* __restrict__ xz, const float* __restrict__ cw,
    const float* __restrict__ cb, unsigned short* __restrict__ outT, int rev)
{
  __shared__ float sx[64][73];
  int l0 = blockIdx.x * 64;
  int d0 = blockIdx.y * 64;
  int b = blockIdx.z;
  int tid = threadIdx.x;
  const float* base = xz + ((size_t)b*2048 + d0)*LL;
  for (int idx = tid; idx < 64*67; idx += 256) {
    int r = idx / 67, i = idx - r*67;
    int lp = l0 - 3 + i;
    float v = 0.f;
    if (lp >= 0) v = base[(size_t)r*LL + (rev ? (LL-1-lp) : lp)];
    sx[r][i] = v;
  }
  __syncthreads();
  int dof = tid & 63;
  int lq = tid >> 6;
  int d = d0 + dof;
  float4 w4 = *(const float4*)(cw + (size_t)d*4);
  float bv = cb[d];
  unsigned short* orow = outT + (size_t)b*LL*1024 + d;
  #pragma unroll
  for (int j=0;j<16;++j){
    int lr = lq + j*4;
    float acc = bv + w4.x*sx[dof][lr] + w4.y*sx[dof][lr+1]
                   + w4.z*sx[dof][lr+2] + w4.w*sx[dof][lr+3];
    orow[(size_t)(l0+lr)*1024] = f2bu(acc * sigmoidf_(acc));
  }
}

// ================= chunked selective scan (lane-owns-channel) =================
__global__ __launch_bounds__(256) void scan1_k(
    const unsigned short* __restrict__ de0, const unsigned short* __restrict__ de1,
    const unsigned short* __restrict__ u0, const unsigned short* __restrict__ u1,
    const float* __restrict__ xd0, const float* __restrict__ xd1,
    const float* __restrict__ al0, const float* __restrict__ al1,
    float* __restrict__ Pbuf, float* __restrict__ Sbuf)
{
  __shared__ float sBC[CS][32];
  int zc = blockIdx.z, dir = zc>>1, b = zc&1;
  const unsigned short* de = dir? de1:de0;
  const unsigned short* uT = dir? u1:u0;
  const float* xd = dir? xd1:xd0;
  const float* al = dir? al1:al0;
  int t = threadIdx.x;
  int d = blockIdx.x*128 + (t>>1);
  int sh = (t&1)*8;
  int l0 = blockIdx.y*CS;
  size_t nrow = (size_t)b*1024 + l0;
  for (int idx = t; idx < CS*32; idx += 256){
    int r = idx >> 5, c = idx & 31;
    sBC[r][c] = xd[(nrow + r)*64 + 32 + c];
  }
  __syncthreads();
  float A[8], h[8], P[8];
  #pragma unroll
  for (int j=0;j<8;++j){ A[j] = -expf(al[d*16 + sh + j]); h[j]=0.f; P[j]=1.f; }
  const unsigned short* dep = de + nrow*1024 + d;
  const unsigned short* up  = uT + nrow*1024 + d;
  for (int l=0; l<CS; ++l){
    float dv = bu2f(dep[(size_t)l*1024]);
    float uv = bu2f(up[(size_t)l*1024]);
    float du = dv*uv;
    #pragma unroll
    for (int j=0;j<8;++j){
      float a = __expf(dv*A[j]);
      h[j] = a*h[j] + du*sBC[l][sh+j];
      P[j] *= a;
    }
  }
  size_t sb = (size_t)blockIdx.y*65536 + (size_t)(zc*1024 + d)*16 + sh;
  *(float4*)&Pbuf[sb]   = make_float4(P[0],P[1],P[2],P[3]);
  *(float4*)&Pbuf[sb+4] = make_float4(P[4],P[5],P[6],P[7]);
  *(float4*)&Sbuf[sb]   = make_float4(h[0],h[1],h[2],h[3]);
  *(float4*)&Sbuf[sb+4] = make_float4(h[4],h[5],h[6],h[7]);
}

__global__ __launch_bounds__(256) void scan2_k(
    const float* __restrict__ Pbuf, const float* __restrict__ Sbuf,
    float* __restrict__ Hbuf)
{
  int seq = blockIdx.x*256 + threadIdx.x;
  float H = 0.f;
  #pragma unroll
  for (int cch=0; cch<NC; ++cch){
    Hbuf[(size_t)cch*65536 + seq] = H;
    H = Pbuf[(size_t)cch*65536 + seq]*H + Sbuf[(size_t)cch*65536 + seq];
  }
}

__global__ __launch_bounds__(256) void scan3_k(
    const unsigned short* __restrict__ de0, const unsigned short* __restrict__ de1,
    const unsigned short* __restrict__ u0, const unsigned short* __restrict__ u1,
    const float* __restrict__ xd0, const float* __restrict__ xd1,
    const float* __restrict__ al0, const float* __restrict__ al1,
    const float* __restrict__ dd0, const float* __restrict__ dd1,
    const float* __restrict__ Hbuf,
    float* __restrict__ y0, float* __restrict__ y1)
{
  __shared__ float sBC[CS][32];
  int zc = blockIdx.z, dir = zc>>1, b = zc&1;
  const unsigned short* de = dir? de1:de0;
  const unsigned short* uT = dir? u1:u0;
  const float* xd = dir? xd1:xd0;
  const float* al = dir? al1:al0;
  const float* DD = dir? dd1:dd0;
  float* y = dir? y1:y0;
  int t = threadIdx.x;
  int d = blockIdx.x*128 + (t>>1);
  int sh = (t&1)*8;
  int l0 = blockIdx.y*CS;
  size_t nrow = (size_t)b*1024 + l0;
  for (int idx = t; idx < CS*32; idx += 256){
    int r = idx >> 5, c = idx & 31;
    sBC[r][c] = xd[(nrow + r)*64 + 32 + c];
  }
  __syncthreads();
  float A[8], h[8];
  size_t sb = (size_t)blockIdx.y*65536 + (size_t)(zc*1024 + d)*16 + sh;
  float4 h03 = *(const float4*)&Hbuf[sb];
  float4 h47 = *(const float4*)&Hbuf[sb+4];
  h[0]=h03.x; h[1]=h03.y; h[2]=h03.z; h[3]=h03.w;
  h[4]=h47.x; h[5]=h47.y; h[6]=h47.z; h[7]=h47.w;
  #pragma unroll
  for (int j=0;j<8;++j) A[j] = -expf(al[d*16 + sh + j]);
  float Dd = DD[d];
  const unsigned short* dep = de + nrow*1024 + d;
  const unsigned short* up  = uT + nrow*1024 + d;
  float* yb = y + (size_t)b*LL*1024 + d;
  for (int l=0; l<CS; ++l){
    float dv = bu2f(dep[(size_t)l*1024]);
    float uv = bu2f(up[(size_t)l*1024]);
    float du = dv*uv;
    float pa = 0.f;
    #pragma unroll
    for (int j=0;j<8;++j){
      float a = __expf(dv*A[j]);
      h[j] = a*h[j] + du*sBC[l][sh+j];
      pa += h[j]*sBC[l][16+sh+j];
    }
    pa += __shfl_xor(pa, 1);
    if ((t&1)==0){
      int lo = dir ? (1023 - l0 - l) : (l0 + l);
      yb[(size_t)lo*1024] = pa + uv*Dd;
    }
  }
}

extern "C" void kernel_launch(void* const* d_in, const int* in_sizes, int n_in,
                              void* d_out, int out_size, void* d_ws, size_t ws_size,
                              hipStream_t stream)
{
  const float* x   = (const float*)d_in[0];
  const float* c1w = (const float*)d_in[1];  const float* c1b = (const float*)d_in[2];
  const float* g1g = (const float*)d_in[3];  const float* g1b = (const float*)d_in[4];
  const float* c2w = (const float*)d_in[5];  const float* c2b = (const float*)d_in[6];
  const float* g2g = (const float*)d_in[7];  const float* g2b = (const float*)d_in[8];
  const float* c3w = (const float*)d_in[9];  const float* c3b = (const float*)d_in[10];
  const float* g3g = (const float*)d_in[11]; const float* g3b = (const float*)d_in[12];
  const float* lng = (const float*)d_in[13]; const float* lnb = (const float*)d_in[14];
  const float* ipw = (const float*)d_in[15]; const float* opw = (const float*)d_in[16];
  const float* cvw[2]  = {(const float*)d_in[17], (const float*)d_in[24]};
  const float* cvb[2]  = {(const float*)d_in[18], (const float*)d_in[25]};
  const float* xpw[2]  = {(const float*)d_in[19], (const float*)d_in[26]};
  const float* dtw[2]  = {(const float*)d_in[20], (const float*)d_in[27]};
  const float* dtb[2]  = {(const float*)d_in[21], (const float*)d_in[28]};
  const float* alog[2] = {(const float*)d_in[22], (const float*)d_in[29]};
  const float* Dp[2]   = {(const float*)d_in[23], (const float*)d_in[30]};

  float* ws = (float*)d_ws;
  // ---- workspace map (floats), total 20185088 fl = 80.74 MB ----
  float* h3  = ws;                         // [0, 1048576) residual
  float* h1  = ws + 1048576;               // stem; later xdb
  float* h2  = ws + 1310720;               // stem
  float* t   = ws + 1835008;               // LN out; later Hb
  float* xzb = ws + 2883584;               // [.., 7077888) xz; x-halves later Pb/Sb
  unsigned short* Wb = (unsigned short*)(ws + 7077888);   // A' splits (<=3145728 bf16)
  unsigned short* Bsb = (unsigned short*)(ws + 8650752);  // B' splits (conv1 overflows into yy)
  float* yy0 = ws + 11796480;
  float* yy1 = ws + 13893632;
  float* PART = ws + 15990784;             // partials; later dl (bf16)
  unsigned short* xcv[2] = { (unsigned short*)(ws + 18087936),
                             (unsigned short*)(ws + 18087936) + 2097152 };
  // aliases
  float* xdb[2] = { ws + 1048576, ws + 1179648 };          // fp32 (b*L,64) each
  unsigned short* dl[2] = { (unsigned short*)PART, (unsigned short*)PART + 2097152 };
  float* Pb = ws + 2883584;                // b0 x-half (dead after dwconv)
  float* Sb = ws + 4980736;                // b1 x-half
  float* Hb = ws + 1835008;                // t (dead after in_proj split)
  float* pxp = ws + 8650752;               // Bs base (free during xp gemm)
  unsigned short* dtB = (unsigned short*)(ws + 9175040);   // Bs + 524288 floats
  float* out = (float*)d_out;

  // ================= CNN stem (split-bf16 MFMA) =================
  ts_split3_k<<<dim3(32,24,2), 256, 0, stream>>>(x, Bsb, 768);
  wsplit3_conv_k<<<384, 256, 0, stream>>>(c1w, Wb, 128, 768);
  gemm_bf3<128,0><<<dim3(32,1,8), 256, 0, stream>>>(Wb, Bsb, nullptr, PART, 128, 2048, 6912);
  reduceK_k<1><<<1024, 256, 0, stream>>>(PART, c1b, nullptr, h1, 128, 2048, 8);
  gn_relu_k<<<64, 256, 0, stream>>>(h1, g1g, g1b, 128, 4);

  ts_split3_k<<<dim3(32,4,2), 256, 0, stream>>>(h1, Bsb, 128);
  wsplit3_conv_k<<<128, 256, 0, stream>>>(c2w, Wb, 256, 128);
  gemm_bf3<128,0><<<dim3(32,2,4), 256, 0, stream>>>(Wb, Bsb, nullptr, PART, 256, 2048, 1152);
  reduceK_k<1><<<2048, 256, 0, stream>>>(PART, c2b, nullptr, h2, 256, 2048, 4);
  gn_relu_k<<<64, 256, 0, stream>>>(h2, g2g, g2b, 256, 8);

  ts_split3_k<<<dim3(32,8,2), 256, 0, stream>>>(h2, Bsb, 256);
  wsplit3_conv_k<<<512, 256, 0, stream>>>(c3w, Wb, 512, 256);
  gemm_bf3<128,0><<<dim3(32,4,2), 256, 0, stream>>>(Wb, Bsb, nullptr, PART, 512, 2048, 2304);
  reduceK_k<1><<<4096, 256, 0, stream>>>(PART, c3b, nullptr, h3, 512, 2048, 2);
  gn_relu_k<<<64, 256, 0, stream>>>(h3, g3g, g3b, 512, 16);

  // ================= LN -> in_proj (split-bf16 MFMA) =================
  ln_k<<<2048, 64, 0, stream>>>(h3, lng, lnb, t);
  split3_k<0><<<1024, 256, 0, stream>>>(ipw, Wb, 2048, 512, 512);
  split3_k<1><<<1024, 256, 0, stream>>>(t, Bsb, 2048, 512, 512);
  gemm_bf3<128,1><<<dim3(32,16,1), 256, 0, stream>>>(Wb, Bsb, nullptr, xzb, 2048, 2048, 1536);

  // ================= per-direction conv/proj/delta =================
  dwconv_k<<<dim3(16,16,2), 256, 0, stream>>>(xzb, cvw[0], cvb[0], xcv[0], 0);
  dwconv_k<<<dim3(16,16,2), 256, 0, stream>>>(xzb, cvw[1], cvb[1], xcv[1], 1);
  for (int s2=0; s2<2; ++s2){
    split1_k<<<64, 256, 0, stream>>>(xpw[s2], Wb, 64, 1024, 1024, 0);
    gemm_bf3<64,0><<<dim3(32,1,4), 256, 0, stream>>>(Wb, xcv[s2], nullptr, pxp, 64, 2048, 1024);
    reduceK_k<0><<<512, 256, 0, stream>>>(pxp, nullptr, nullptr, xdb[s2], 64, 2048, 4);
    split1_k<<<32, 256, 0, stream>>>(dtw[s2], Wb, 1024, 32, 32, 0);
    split1_k<<<64, 256, 0, stream>>>(xdb[s2], dtB, 2048, 32, 64, 0);
    gemm_bf3<128,2><<<dim3(32,8,1), 256, 0, stream>>>(Wb, dtB, dtb[s2], dl[s2], 1024, 2048, 32);
  }

  // ================= chunked selective scan =================
  scan1_k<<<dim3(8,NC,4), 256, 0, stream>>>(
      dl[0], dl[1], xcv[0], xcv[1], xdb[0], xdb[1], alog[0], alog[1], Pb, Sb);
  scan2_k<<<256, 256, 0, stream>>>(Pb, Sb, Hb);
  scan3_k<<<dim3(8,NC,4), 256, 0, stream>>>(
      dl[0], dl[1], xcv[0], xcv[1], xdb[0], xdb[1], alog[0], alog[1],
      Dp[0], Dp[1], Hb, yy0, yy1);

  // ================= gate + out_proj (bf16 MFMA) + residual =================
  gated_split_k<<<dim3(32,32,2), 256, 0, stream>>>(yy0, yy1, xzb, Bsb);
  split1_k<<<512, 256, 0, stream>>>(opw, Wb, 512, 1024, 1024, 0);
  gemm_bf3<128,0><<<dim3(32,4,2), 256, 0, stream>>>(Wb, Bsb, nullptr, PART, 512, 2048, 1024);
  reduceK_k<2><<<4096, 256, 0, stream>>>(PART, nullptr, h3, out, 512, 2048, 2);
}

// Round 8
// 492.455 us; speedup vs baseline: 2.0928x; 1.1011x over previous
//
#include <hip/hip_runtime.h>
#include <hip/hip_bf16.h>
#include <math.h>

#define LL 1024
#define NC 16
#define CS 64

typedef __attribute__((ext_vector_type(8))) short short8_t;
typedef __attribute__((ext_vector_type(4))) float f32x4;

__device__ __forceinline__ float sigmoidf_(float x){ return 1.f/(1.f+__expf(-x)); }
__device__ __forceinline__ unsigned short f2bu(float x){
  unsigned int u = __float_as_uint(x);
  unsigned int r = (u + 0x7fffu + ((u>>16)&1u)) >> 16;
  return (unsigned short)r;
}
__device__ __forceinline__ float bu2f(unsigned short u){
  return __uint_as_float(((unsigned int)u)<<16);
}
// async global->LDS, 16B per lane; LDS dest = uniform base + lane*16
__device__ __forceinline__ void gl2lds16(const void* g, void* l){
  __builtin_amdgcn_global_load_lds(
      (const __attribute__((address_space(1))) unsigned int*)g,
      (__attribute__((address_space(3))) unsigned int*)l, 16, 0, 0);
}

// ---------------- GroupNorm(32) + ReLU, in place ----------------
__global__ __launch_bounds__(256) void gn_relu_k(
    float* __restrict__ io, const float* __restrict__ g, const float* __restrict__ bt,
    int C, int Cg)
{
  int b = blockIdx.x >> 5;
  int grp = blockIdx.x & 31;
  int n = Cg * LL;
  float* p = io + ((size_t)b*C + (size_t)grp*Cg)*LL;
  int tid = threadIdx.x;
  float s=0.f, s2=0.f;
  for (int i=tid; i<n; i+=256){ float v=p[i]; s+=v; s2+=v*v; }
  __shared__ float red[10];
  #pragma unroll
  for (int off=32; off; off>>=1){ s+=__shfl_down(s,off); s2+=__shfl_down(s2,off); }
  if ((tid&63)==0){ red[tid>>6]=s; red[4+(tid>>6)]=s2; }
  __syncthreads();
  if (tid==0){
    float S=red[0]+red[1]+red[2]+red[3];
    float S2=red[4]+red[5]+red[6]+red[7];
    float mean = S/(float)n;
    float var = S2/(float)n - mean*mean;
    red[8]=mean; red[9]=rsqrtf(var+1e-5f);
  }
  __syncthreads();
  float mean=red[8], rstd=red[9];
  const float* gp = g + grp*Cg;
  const float* bp = bt + grp*Cg;
  for (int i=tid; i<n; i+=256){
    int co = i >> 10;
    float v = (p[i]-mean)*rstd*gp[co] + bp[co];
    p[i] = fmaxf(v, 0.f);
  }
}

// ---------------- LayerNorm over C=512 per (b,l) ----------------
__global__ __launch_bounds__(64) void ln_k(
    const float* __restrict__ h, const float* __restrict__ g, const float* __restrict__ bt,
    float* __restrict__ tout)
{
  int bl = blockIdx.x;
  int b = bl >> 10, l = bl & 1023;
  int lane = threadIdx.x;
  const float* base = h + (size_t)b*512*LL + l;
  float v[8]; float s=0.f, s2=0.f;
  #pragma unroll
  for (int j=0;j<8;++j){ v[j] = base[(size_t)(lane + j*64)*LL]; s+=v[j]; s2+=v[j]*v[j]; }
  #pragma unroll
  for (int off=32; off; off>>=1){ s+=__shfl_xor(s,off); s2+=__shfl_xor(s2,off); }
  float mean = s*(1.f/512.f);
  float rstd = rsqrtf(s2*(1.f/512.f) - mean*mean + 1e-5f);
  float* o = tout + (size_t)bl*512;
  #pragma unroll
  for (int j=0;j<8;++j){ int c = lane + j*64; o[c] = (v[j]-mean)*rstd*g[c] + bt[c]; }
}

// ---------------- split-K reduce ----------------
// MODE 0: out[i]=s ; MODE 1: out[(b*M+m)*LL+l]=s+bias[m] ; MODE 2: +res
// MODE 3: out[i]=s AND d16[n*32+c]=bf16(s) for c<32 (M must be 64)
template<int MODE>
__global__ __launch_bounds__(256) void reduceK_k(
    const float* __restrict__ P, const float* __restrict__ bias,
    const float* __restrict__ res, float* __restrict__ out,
    int M, int N, int KS, unsigned short* __restrict__ d16)
{
  int i = blockIdx.x*256 + threadIdx.x;
  if (i >= N*M) return;
  float s = 0.f;
  for (int k=0;k<KS;++k) s += P[(size_t)k*((size_t)N*M) + i];
  if (MODE==0){ out[i] = s; return; }
  if (MODE==3){
    out[i] = s;
    int c = i & 63;
    if (c < 32) d16[(size_t)(i>>6)*32 + c] = f2bu(s);
    return;
  }
  int n = i / M, m = i - n*M;
  int b = n >> 10, l = n & 1023;
  size_t o = ((size_t)b*M + m)*LL + l;
  if (MODE==1) out[o] = s + bias[m];
  else         out[o] = s + res[o];
}

// -------- stem B': transpose + split3, k = tap*Cin + ci, pattern [hi|hi|lo] ------
__global__ __launch_bounds__(256) void ts_split3_k(
    const float* __restrict__ src, unsigned short* __restrict__ dst, int Cin)
{
  __shared__ float sx[32][35];
  int b = blockIdx.z;
  int l0 = blockIdx.x*32, ci0 = blockIdx.y*32;
  int tid = threadIdx.x;
  const float* sb = src + ((size_t)b*Cin + ci0)*LL;
  for (int idx = tid; idx < 32*34; idx += 256){
    int r = idx / 34, c = idx - r*34;
    int lp = l0 - 1 + c;
    sx[r][c] = (lp >= 0 && lp < LL) ? sb[(size_t)r*LL + lp] : 0.f;
  }
  __syncthreads();
  int K = 3*Cin, K3 = 9*Cin;
  int lr = tid >> 5, cl = tid & 31;
  #pragma unroll
  for (int p=0;p<4;++p){
    int l = lr + p*8;
    unsigned short* drow = dst + (size_t)(b*LL + l0 + l)*K3;
    #pragma unroll
    for (int tap=0; tap<3; ++tap){
      float v = sx[cl][l + tap];
      unsigned short hi = f2bu(v);
      unsigned short lo = f2bu(v - bu2f(hi));
      int kk = tap*Cin + ci0 + cl;
      drow[kk] = hi; drow[K + kk] = hi; drow[2*K + kk] = lo;
    }
  }
}

// -------- conv weights A': [Cout][3K] tap-major, pattern [hi|lo|hi] ------
__global__ __launch_bounds__(256) void wsplit3_conv_k(
    const float* __restrict__ w, unsigned short* __restrict__ dst, int Cout, int Cin)
{
  int i = blockIdx.x*256 + threadIdx.x;
  if (i >= Cout*Cin) return;
  int co = i / Cin, ci = i - co*Cin;
  int K = 3*Cin, K3 = 9*Cin;
  unsigned short* drow = dst + (size_t)co*K3;
  #pragma unroll
  for (int tap=0; tap<3; ++tap){
    float v = w[(size_t)(co*Cin + ci)*3 + tap];
    unsigned short hi = f2bu(v);
    unsigned short lo = f2bu(v - bu2f(hi));
    int kk = tap*Cin + ci;
    drow[kk] = hi; drow[K + kk] = lo; drow[2*K + kk] = hi;
  }
}

// -------- row-major split3: PAT 0 = A-side [hi|lo|hi], PAT 1 = B-side [hi|hi|lo]
template<int PAT>
__global__ __launch_bounds__(256) void split3_k(
    const float* __restrict__ src, unsigned short* __restrict__ dst,
    int R, int K, int ld)
{
  int i = blockIdx.x*256 + threadIdx.x;
  int kq = K >> 2;
  if (i >= R*kq) return;
  int r = i / kq, k4 = (i - r*kq)*4;
  float4 v = *(const float4*)&src[(size_t)r*ld + k4];
  float vv[4] = {v.x, v.y, v.z, v.w};
  unsigned short hi[4], lo[4];
  #pragma unroll
  for (int j=0;j<4;++j){ hi[j]=f2bu(vv[j]); lo[j]=f2bu(vv[j]-bu2f(hi[j])); }
  unsigned short* d0 = dst + (size_t)r*3*K + k4;
  ushort4 h4 = make_ushort4(hi[0],hi[1],hi[2],hi[3]);
  ushort4 l4 = make_ushort4(lo[0],lo[1],lo[2],lo[3]);
  *(ushort4*)d0 = h4;
  *(ushort4*)(d0 + K)   = (PAT==0) ? l4 : h4;
  *(ushort4*)(d0 + 2*K) = (PAT==0) ? h4 : l4;
}

// -------- plain hi split (bf16 cast), cols [k0, k0+K) --------
__global__ __launch_bounds__(256) void split1_k(
    const float* __restrict__ src, unsigned short* __restrict__ dst,
    int R, int K, int ld, int k0)
{
  int i = blockIdx.x*256 + threadIdx.x;
  int kq = K >> 2;
  if (i >= R*kq) return;
  int r = i / kq, k4 = (i - r*kq)*4;
  float4 v = *(const float4*)&src[(size_t)r*ld + k0 + k4];
  *(ushort4*)(dst + (size_t)r*K + k4) =
      make_ushort4(f2bu(v.x), f2bu(v.y), f2bu(v.z), f2bu(v.w));
}

// -------- out-proj B: hi((y0+y1)*silu(z)), z transposed from xz --------
__global__ __launch_bounds__(256) void gated_split_k(
    const float* __restrict__ y0, const float* __restrict__ y1,
    const float* __restrict__ xz, unsigned short* __restrict__ dst)
{
  __shared__ float sz[32][33];
  int b = blockIdx.z;
  int l0 = blockIdx.x*32, d0 = blockIdx.y*32;
  int tid = threadIdx.x;
  const float* zb = xz + ((size_t)b*2048 + 1024 + d0)*LL + l0;
  for (int idx = tid; idx < 1024; idx += 256){
    int r = idx >> 5, c = idx & 31;
    sz[r][c] = zb[(size_t)r*LL + c];
  }
  __syncthreads();
  int lr = tid >> 5, dd = tid & 31;
  #pragma unroll
  for (int p=0;p<4;++p){
    int l = lr + p*8;
    size_t n = (size_t)b*LL + l0 + l;
    float zv = sz[dd][l];
    float y = y0[n*1024 + d0 + dd] + y1[n*1024 + d0 + dd];
    dst[n*1024 + d0 + dd] = f2bu(y * (zv * sigmoidf_(zv)));
  }
}

// ---------------- bf16 MFMA GEMM (m97 structure): C[n][m] = sum_k B[n][k]*A[m][k] --
// global_load_lds 16B staging, linear LDS, XOR-swizzled via pre-swizzled global src.
// BK=64: row=128B, swz = c ^ (row&7). BK=32: row=64B, swz = c ^ ((row>>1)&3).
// EPI 0: fp32 partials P[z][n*M+m]; EPI 1: C[(b*M+m)*LL+l]; EPI 2: bf16 softplus
template<int BM, int BK, int EPI>
__global__ __launch_bounds__(256) void gemm_bf3(
    const unsigned short* __restrict__ A, const unsigned short* __restrict__ B,
    const float* __restrict__ bias, void* __restrict__ Cv,
    int M, int N, int K3)
{
  constexpr int BN = 64;
  constexpr int RB = 2*BK;            // bytes per LDS row
  constexpr int RPL = 1024/RB;        // rows covered per wave-load (8 or 16)
  constexpr int ALD = BM/RPL;         // A wave-loads per k-step
  constexpr int BLD = BN/RPL;
  constexpr int NL = ALD + BLD;
  constexpr int FM = BM/32;
  constexpr int KH = BK/32;
  __shared__ __align__(16) char smem[(BM+BN)*RB];
  char* As = smem;
  char* Bs = smem + BM*RB;
  int tid = threadIdx.x;
  int w = tid >> 6, lane = tid & 63;
  int wm = w & 1, wn = w >> 1;
  int n0 = blockIdx.x*BN, m0 = blockIdx.y*BM;
  int kper = K3 / gridDim.z;
  int kbeg = blockIdx.z * kper;

  // per-lane staging source offset (elements): row-in-group * K3 + srcchunk*8
  int lr, sc;
  if (BK == 64){ lr = lane>>3; sc = (lane&7) ^ lr; }
  else         { lr = lane>>2; sc = (lane&3) ^ ((lr>>1)&3); }
  size_t lsrc = (size_t)lr*K3 + sc*8;

  f32x4 acc[FM][2];
  #pragma unroll
  for (int i=0;i<FM;++i){ acc[i][0] = (f32x4){0,0,0,0}; acc[i][1] = (f32x4){0,0,0,0}; }

  int r16 = lane & 15, g4 = lane >> 4;
  for (int k = kbeg; k < kbeg + kper; k += BK){
    // ---- stage A,B tiles direct to LDS (async, drained by barrier) ----
    for (int j = w; j < NL; j += 4){
      if (j < ALD){
        gl2lds16(A + (size_t)(m0 + j*RPL)*K3 + k + lsrc, As + j*(RPL*RB));
      } else {
        int jb = j - ALD;
        gl2lds16(B + (size_t)(n0 + jb*RPL)*K3 + k + lsrc, Bs + jb*(RPL*RB));
      }
    }
    __syncthreads();
    #pragma unroll
    for (int kh=0; kh<KH; ++kh){
      int c = kh*4 + g4;
      int rb0 = wn*32 + r16, rb1 = rb0 + 16;
      int pb0 = (BK==64) ? (c ^ (rb0&7)) : (c ^ ((rb0>>1)&3));
      int pb1 = (BK==64) ? (c ^ (rb1&7)) : (c ^ ((rb1>>1)&3));
      short8_t bf0 = *(short8_t*)&Bs[rb0*RB + pb0*16];
      short8_t bf1 = *(short8_t*)&Bs[rb1*RB + pb1*16];
      #pragma unroll
      for (int i2=0;i2<FM;++i2){
        int ra = wm*(BM/2) + i2*16 + r16;
        int pa = (BK==64) ? (c ^ (ra&7)) : (c ^ ((ra>>1)&3));
        short8_t af = *(short8_t*)&As[ra*RB + pa*16];
        acc[i2][0] = __builtin_amdgcn_mfma_f32_16x16x32_bf16(af, bf0, acc[i2][0], 0,0,0);
        acc[i2][1] = __builtin_amdgcn_mfma_f32_16x16x32_bf16(af, bf1, acc[i2][1], 0,0,0);
      }
    }
    __syncthreads();
  }
  #pragma unroll
  for (int i2=0;i2<FM;++i2){
    #pragma unroll
    for (int j=0;j<2;++j){
      #pragma unroll
      for (int r=0;r<4;++r){
        int m = m0 + wm*(BM/2) + i2*16 + (g4*4 + r);
        int n = n0 + wn*32 + j*16 + r16;
        float v = acc[i2][j][r];
        if (EPI==0){
          ((float*)Cv)[(size_t)blockIdx.z*((size_t)N*M) + (size_t)n*M + m] = v;
        } else if (EPI==1){
          int b = n>>10, l = n&1023;
          ((float*)Cv)[((size_t)b*M + m)*LL + l] = v;
        } else {
          float xv = v + bias[m];
          float sp = (xv > 20.f) ? xv : log1pf(__expf(xv));
          ((unsigned short*)Cv)[(size_t)n*M + m] = f2bu(sp);
        }
      }
    }
  }
}

// -------- causal depthwise conv k4 + SiLU, bf16 transposed out (b,l,d) ------
__global__ __launch_bounds__(256) void dwconv_k(
    const float* __restrict__ xz, const float* __restrict__ cw,
    const float* __restrict__ cb, unsigned short* __restrict__ outT, int rev)
{
  __shared__ float sx[64][73];
  int l0 = blockIdx.x * 64;
  int d0 = blockIdx.y * 64;
  int b = blockIdx.z;
  int tid = threadIdx.x;
  const float* base = xz + ((size_t)b*2048 + d0)*LL;
  for (int idx = tid; idx < 64*67; idx += 256) {
    int r = idx / 67, i = idx - r*67;
    int lp = l0 - 3 + i;
    float v = 0.f;
    if (lp >= 0) v = base[(size_t)r*LL + (rev ? (LL-1-lp) : lp)];
    sx[r][i] = v;
  }
  __syncthreads();
  int dof = tid & 63;
  int lq = tid >> 6;
  int d = d0 + dof;
  float4 w4 = *(const float4*)(cw + (size_t)d*4);
  float bv = cb[d];
  unsigned short* orow = outT + (size_t)b*LL*1024 + d;
  #pragma unroll
  for (int j=0;j<16;++j){
    int lr = lq + j*4;
    float acc = bv + w4.x*sx[dof][lr] + w4.y*sx[dof][lr+1]
                   + w4.z*sx[dof][lr+2] + w4.w*sx[dof][lr+3];
    orow[(size_t)(l0+lr)*1024] = f2bu(acc * sigmoidf_(acc));
  }
}

// ================= chunked selective scan (lane-owns-channel) =================
__global__ __launch_bounds__(256) void scan1_k(
    const unsigned short* __restrict__ de0, const unsigned short* __restrict__ de1,
    const unsigned short* __restrict__ u0, const unsigned short* __restrict__ u1,
    const float* __restrict__ xd0, const float* __restrict__ xd1,
    const float* __restrict__ al0, const float* __restrict__ al1,
    float* __restrict__ Pbuf, float* __restrict__ Sbuf)
{
  __shared__ float sBC[CS][32];
  int zc = blockIdx.z, dir = zc>>1, b = zc&1;
  const unsigned short* de = dir? de1:de0;
  const unsigned short* uT = dir? u1:u0;
  const float* xd = dir? xd1:xd0;
  const float* al = dir? al1:al0;
  int t = threadIdx.x;
  int d = blockIdx.x*128 + (t>>1);
  int sh = (t&1)*8;
  int l0 = blockIdx.y*CS;
  size_t nrow = (size_t)b*1024 + l0;
  for (int idx = t; idx < CS*32; idx += 256){
    int r = idx >> 5, c = idx & 31;
    sBC[r][c] = xd[(nrow + r)*64 + 32 + c];
  }
  __syncthreads();
  float A[8], h[8], P[8];
  #pragma unroll
  for (int j=0;j<8;++j){ A[j] = -expf(al[d*16 + sh + j]); h[j]=0.f; P[j]=1.f; }
  const unsigned short* dep = de + nrow*1024 + d;
  const unsigned short* up  = uT + nrow*1024 + d;
  for (int l=0; l<CS; ++l){
    float dv = bu2f(dep[(size_t)l*1024]);
    float uv = bu2f(up[(size_t)l*1024]);
    float du = dv*uv;
    #pragma unroll
    for (int j=0;j<8;++j){
      float a = __expf(dv*A[j]);
      h[j] = a*h[j] + du*sBC[l][sh+j];
      P[j] *= a;
    }
  }
  size_t sb = (size_t)blockIdx.y*65536 + (size_t)(zc*1024 + d)*16 + sh;
  *(float4*)&Pbuf[sb]   = make_float4(P[0],P[1],P[2],P[3]);
  *(float4*)&Pbuf[sb+4] = make_float4(P[4],P[5],P[6],P[7]);
  *(float4*)&Sbuf[sb]   = make_float4(h[0],h[1],h[2],h[3]);
  *(float4*)&Sbuf[sb+4] = make_float4(h[4],h[5],h[6],h[7]);
}

__global__ __launch_bounds__(256) void scan2_k(
    const float* __restrict__ Pbuf, const float* __restrict__ Sbuf,
    float* __restrict__ Hbuf)
{
  int seq = blockIdx.x*256 + threadIdx.x;
  float H = 0.f;
  #pragma unroll
  for (int cch=0; cch<NC; ++cch){
    Hbuf[(size_t)cch*65536 + seq] = H;
    H = Pbuf[(size_t)cch*65536 + seq]*H + Sbuf[(size_t)cch*65536 + seq];
  }
}

__global__ __launch_bounds__(256) void scan3_k(
    const unsigned short* __restrict__ de0, const unsigned short* __restrict__ de1,
    const unsigned short* __restrict__ u0, const unsigned short* __restrict__ u1,
    const float* __restrict__ xd0, const float* __restrict__ xd1,
    const float* __restrict__ al0, const float* __restrict__ al1,
    const float* __restrict__ dd0, const float* __restrict__ dd1,
    const float* __restrict__ Hbuf,
    float* __restrict__ y0, float* __restrict__ y1)
{
  __shared__ float sBC[CS][32];
  int zc = blockIdx.z, dir = zc>>1, b = zc&1;
  const unsigned short* de = dir? de1:de0;
  const unsigned short* uT = dir? u1:u0;
  const float* xd = dir? xd1:xd0;
  const float* al = dir? al1:al0;
  const float* DD = dir? dd1:dd0;
  float* y = dir? y1:y0;
  int t = threadIdx.x;
  int d = blockIdx.x*128 + (t>>1);
  int sh = (t&1)*8;
  int l0 = blockIdx.y*CS;
  size_t nrow = (size_t)b*1024 + l0;
  for (int idx = t; idx < CS*32; idx += 256){
    int r = idx >> 5, c = idx & 31;
    sBC[r][c] = xd[(nrow + r)*64 + 32 + c];
  }
  __syncthreads();
  float A[8], h[8];
  size_t sb = (size_t)blockIdx.y*65536 + (size_t)(zc*1024 + d)*16 + sh;
  float4 h03 = *(const float4*)&Hbuf[sb];
  float4 h47 = *(const float4*)&Hbuf[sb+4];
  h[0]=h03.x; h[1]=h03.y; h[2]=h03.z; h[3]=h03.w;
  h[4]=h47.x; h[5]=h47.y; h[6]=h47.z; h[7]=h47.w;
  #pragma unroll
  for (int j=0;j<8;++j) A[j] = -expf(al[d*16 + sh + j]);
  float Dd = DD[d];
  const unsigned short* dep = de + nrow*1024 + d;
  const unsigned short* up  = uT + nrow*1024 + d;
  float* yb = y + (size_t)b*LL*1024 + d;
  for (int l=0; l<CS; ++l){
    float dv = bu2f(dep[(size_t)l*1024]);
    float uv = bu2f(up[(size_t)l*1024]);
    float du = dv*uv;
    float pa = 0.f;
    #pragma unroll
    for (int j=0;j<8;++j){
      float a = __expf(dv*A[j]);
      h[j] = a*h[j] + du*sBC[l][sh+j];
      pa += h[j]*sBC[l][16+sh+j];
    }
    pa += __shfl_xor(pa, 1);
    if ((t&1)==0){
      int lo = dir ? (1023 - l0 - l) : (l0 + l);
      yb[(size_t)lo*1024] = pa + uv*Dd;
    }
  }
}

extern "C" void kernel_launch(void* const* d_in, const int* in_sizes, int n_in,
                              void* d_out, int out_size, void* d_ws, size_t ws_size,
                              hipStream_t stream)
{
  const float* x   = (const float*)d_in[0];
  const float* c1w = (const float*)d_in[1];  const float* c1b = (const float*)d_in[2];
  const float* g1g = (const float*)d_in[3];  const float* g1b = (const float*)d_in[4];
  const float* c2w = (const float*)d_in[5];  const float* c2b = (const float*)d_in[6];
  const float* g2g = (const float*)d_in[7];  const float* g2b = (const float*)d_in[8];
  const float* c3w = (const float*)d_in[9];  const float* c3b = (const float*)d_in[10];
  const float* g3g = (const float*)d_in[11]; const float* g3b = (const float*)d_in[12];
  const float* lng = (const float*)d_in[13]; const float* lnb = (const float*)d_in[14];
  const float* ipw = (const float*)d_in[15]; const float* opw = (const float*)d_in[16];
  const float* cvw[2]  = {(const float*)d_in[17], (const float*)d_in[24]};
  const float* cvb[2]  = {(const float*)d_in[18], (const float*)d_in[25]};
  const float* xpw[2]  = {(const float*)d_in[19], (const float*)d_in[26]};
  const float* dtw[2]  = {(const float*)d_in[20], (const float*)d_in[27]};
  const float* dtb[2]  = {(const float*)d_in[21], (const float*)d_in[28]};
  const float* alog[2] = {(const float*)d_in[22], (const float*)d_in[29]};
  const float* Dp[2]   = {(const float*)d_in[23], (const float*)d_in[30]};

  float* ws = (float*)d_ws;
  // ---- workspace map (floats), total 20185088 fl = 80.74 MB ----
  float* h3  = ws;                         // [0, 1048576) residual
  float* h1  = ws + 1048576;               // stem; later xdb
  float* h2  = ws + 1310720;               // stem
  float* t   = ws + 1835008;               // LN out; later Hb
  float* xzb = ws + 2883584;               // [.., 7077888) xz; x-halves later Pb/Sb
  unsigned short* Wb = (unsigned short*)(ws + 7077888);   // A' splits (<=3145728 bf16)
  unsigned short* Bsb = (unsigned short*)(ws + 8650752);  // B' splits (conv1 overflows into yy)
  float* yy0 = ws + 11796480;
  float* yy1 = ws + 13893632;
  float* PART = ws + 15990784;             // partials; later dl (bf16)
  unsigned short* xcv[2] = { (unsigned short*)(ws + 18087936),
                             (unsigned short*)(ws + 18087936) + 2097152 };
  // aliases
  float* xdb[2] = { ws + 1048576, ws + 1179648 };          // fp32 (b*L,64) each
  unsigned short* dl[2] = { (unsigned short*)PART, (unsigned short*)PART + 2097152 };
  float* Pb = ws + 2883584;                // b0 x-half (dead after dwconv)
  float* Sb = ws + 4980736;                // b1 x-half
  float* Hb = ws + 1835008;                // t (dead after in_proj split)
  float* pxp = ws + 8650752;               // Bs base (free during xp gemm)
  unsigned short* dtB = (unsigned short*)(ws + 9175040);   // Bs + 524288 floats
  float* out = (float*)d_out;

  // ================= CNN stem (split-bf16 MFMA) =================
  ts_split3_k<<<dim3(32,24,2), 256, 0, stream>>>(x, Bsb, 768);
  wsplit3_conv_k<<<384, 256, 0, stream>>>(c1w, Wb, 128, 768);
  gemm_bf3<64,64,0><<<dim3(32,2,4), 256, 0, stream>>>(Wb, Bsb, nullptr, PART, 128, 2048, 6912);
  reduceK_k<1><<<1024, 256, 0, stream>>>(PART, c1b, nullptr, h1, 128, 2048, 4, nullptr);
  gn_relu_k<<<64, 256, 0, stream>>>(h1, g1g, g1b, 128, 4);

  ts_split3_k<<<dim3(32,4,2), 256, 0, stream>>>(h1, Bsb, 128);
  wsplit3_conv_k<<<128, 256, 0, stream>>>(c2w, Wb, 256, 128);
  gemm_bf3<64,64,0><<<dim3(32,4,2), 256, 0, stream>>>(Wb, Bsb, nullptr, PART, 256, 2048, 1152);
  reduceK_k<1><<<2048, 256, 0, stream>>>(PART, c2b, nullptr, h2, 256, 2048, 2, nullptr);
  gn_relu_k<<<64, 256, 0, stream>>>(h2, g2g, g2b, 256, 8);

  ts_split3_k<<<dim3(32,8,2), 256, 0, stream>>>(h2, Bsb, 256);
  wsplit3_conv_k<<<512, 256, 0, stream>>>(c3w, Wb, 512, 256);
  gemm_bf3<128,64,0><<<dim3(32,4,2), 256, 0, stream>>>(Wb, Bsb, nullptr, PART, 512, 2048, 2304);
  reduceK_k<1><<<4096, 256, 0, stream>>>(PART, c3b, nullptr, h3, 512, 2048, 2, nullptr);
  gn_relu_k<<<64, 256, 0, stream>>>(h3, g3g, g3b, 512, 16);

  // ================= LN -> in_proj (split-bf16 MFMA) =================
  ln_k<<<2048, 64, 0, stream>>>(h3, lng, lnb, t);
  split3_k<0><<<1024, 256, 0, stream>>>(ipw, Wb, 2048, 512, 512);
  split3_k<1><<<1024, 256, 0, stream>>>(t, Bsb, 2048, 512, 512);
  gemm_bf3<128,64,1><<<dim3(32,16,1), 256, 0, stream>>>(Wb, Bsb, nullptr, xzb, 2048, 2048, 1536);

  // ================= per-direction conv/proj/delta =================
  dwconv_k<<<dim3(16,16,2), 256, 0, stream>>>(xzb, cvw[0], cvb[0], xcv[0], 0);
  dwconv_k<<<dim3(16,16,2), 256, 0, stream>>>(xzb, cvw[1], cvb[1], xcv[1], 1);
  for (int s2=0; s2<2; ++s2){
    split1_k<<<64, 256, 0, stream>>>(xpw[s2], Wb, 64, 1024, 1024, 0);
    gemm_bf3<64,64,0><<<dim3(32,1,4), 256, 0, stream>>>(Wb, xcv[s2], nullptr, pxp, 64, 2048, 1024);
    reduceK_k<3><<<512, 256, 0, stream>>>(pxp, nullptr, nullptr, xdb[s2], 64, 2048, 4, dtB);
    split1_k<<<32, 256, 0, stream>>>(dtw[s2], Wb, 1024, 32, 32, 0);
    gemm_bf3<128,32,2><<<dim3(32,8,1), 256, 0, stream>>>(Wb, dtB, dtb[s2], dl[s2], 1024, 2048, 32);
  }

  // ================= chunked selective scan =================
  scan1_k<<<dim3(8,NC,4), 256, 0, stream>>>(
      dl[0], dl[1], xcv[0], xcv[1], xdb[0], xdb[1], alog[0], alog[1], Pb, Sb);
  scan2_k<<<256, 256, 0, stream>>>(Pb, Sb, Hb);
  scan3_k<<<dim3(8,NC,4), 256, 0, stream>>>(
      dl[0], dl[1], xcv[0], xcv[1], xdb[0], xdb[1], alog[0], alog[1],
      Dp[0], Dp[1], Hb, yy0, yy1);

  // ================= gate + out_proj (bf16 MFMA) + residual =================
  gated_split_k<<<dim3(32,32,2), 256, 0, stream>>>(yy0, yy1, xzb, Bsb);
  split1_k<<<512, 256, 0, stream>>>(opw, Wb, 512, 1024, 1024, 0);
  gemm_bf3<128,64,0><<<dim3(32,4,2), 256, 0, stream>>>(Wb, Bsb, nullptr, PART, 512, 2048, 1024);
  reduceK_k<2><<<4096, 256, 0, stream>>>(PART, nullptr, h3, out, 512, 2048, 2, nullptr);
}

// Round 9
// 460.671 us; speedup vs baseline: 2.2372x; 1.0690x over previous
//
#include <hip/hip_runtime.h>
#include <hip/hip_bf16.h>
#include <math.h>

#define LL 1024
#define NC 16
#define CS 64

typedef __attribute__((ext_vector_type(8))) short short8_t;
typedef __attribute__((ext_vector_type(4))) float f32x4;

__device__ __forceinline__ float sigmoidf_(float x){ return 1.f/(1.f+__expf(-x)); }
__device__ __forceinline__ unsigned short f2bu(float x){
  unsigned int u = __float_as_uint(x);
  unsigned int r = (u + 0x7fffu + ((u>>16)&1u)) >> 16;
  return (unsigned short)r;
}
__device__ __forceinline__ float bu2f(unsigned short u){
  return __uint_as_float(((unsigned int)u)<<16);
}
__device__ __forceinline__ void gl2lds16(const void* g, void* l){
  __builtin_amdgcn_global_load_lds(
      (const __attribute__((address_space(1))) unsigned int*)g,
      (__attribute__((address_space(3))) unsigned int*)l, 16, 0, 0);
}

// ---------------- GroupNorm(32) + ReLU, in place ----------------
__global__ __launch_bounds__(256) void gn_relu_k(
    float* __restrict__ io, const float* __restrict__ g, const float* __restrict__ bt,
    int C, int Cg)
{
  int b = blockIdx.x >> 5;
  int grp = blockIdx.x & 31;
  int n = Cg * LL;
  float* p = io + ((size_t)b*C + (size_t)grp*Cg)*LL;
  int tid = threadIdx.x;
  float s=0.f, s2=0.f;
  for (int i=tid; i<n; i+=256){ float v=p[i]; s+=v; s2+=v*v; }
  __shared__ float red[10];
  #pragma unroll
  for (int off=32; off; off>>=1){ s+=__shfl_down(s,off); s2+=__shfl_down(s2,off); }
  if ((tid&63)==0){ red[tid>>6]=s; red[4+(tid>>6)]=s2; }
  __syncthreads();
  if (tid==0){
    float S=red[0]+red[1]+red[2]+red[3];
    float S2=red[4]+red[5]+red[6]+red[7];
    float mean = S/(float)n;
    float var = S2/(float)n - mean*mean;
    red[8]=mean; red[9]=rsqrtf(var+1e-5f);
  }
  __syncthreads();
  float mean=red[8], rstd=red[9];
  const float* gp = g + grp*Cg;
  const float* bp = bt + grp*Cg;
  for (int i=tid; i<n; i+=256){
    int co = i >> 10;
    float v = (p[i]-mean)*rstd*gp[co] + bp[co];
    p[i] = fmaxf(v, 0.f);
  }
}

// ------- fused LayerNorm + B-side split3 ([hi|hi|lo]) over C=512 per (b,l) -------
__global__ __launch_bounds__(64) void ln_split_k(
    const float* __restrict__ h, const float* __restrict__ g, const float* __restrict__ bt,
    unsigned short* __restrict__ dst)
{
  int bl = blockIdx.x;
  int b = bl >> 10, l = bl & 1023;
  int lane = threadIdx.x;
  const float* base = h + (size_t)b*512*LL + l;
  float v[8]; float s=0.f, s2=0.f;
  #pragma unroll
  for (int j=0;j<8;++j){ v[j] = base[(size_t)(lane*8 + j)*LL]; s+=v[j]; s2+=v[j]*v[j]; }
  #pragma unroll
  for (int off=32; off; off>>=1){ s+=__shfl_xor(s,off); s2+=__shfl_xor(s2,off); }
  float mean = s*(1.f/512.f);
  float rstd = rsqrtf(s2*(1.f/512.f) - mean*mean + 1e-5f);
  unsigned short hi[8], lo[8];
  #pragma unroll
  for (int j=0;j<8;++j){
    int c = lane*8 + j;
    float f = (v[j]-mean)*rstd*g[c] + bt[c];
    hi[j] = f2bu(f); lo[j] = f2bu(f - bu2f(hi[j]));
  }
  unsigned short* row = dst + (size_t)bl*1536 + lane*8;
  *(ushort4*)&row[0] = make_ushort4(hi[0],hi[1],hi[2],hi[3]);
  *(ushort4*)&row[4] = make_ushort4(hi[4],hi[5],hi[6],hi[7]);
  *(ushort4*)&row[512] = make_ushort4(hi[0],hi[1],hi[2],hi[3]);
  *(ushort4*)&row[516] = make_ushort4(hi[4],hi[5],hi[6],hi[7]);
  *(ushort4*)&row[1024] = make_ushort4(lo[0],lo[1],lo[2],lo[3]);
  *(ushort4*)&row[1028] = make_ushort4(lo[4],lo[5],lo[6],lo[7]);
}

// ---------------- split-K reduce: MODE 1 bias, MODE 2 residual ----------------
template<int MODE>
__global__ __launch_bounds__(256) void reduceK_k(
    const float* __restrict__ P, const float* __restrict__ bias,
    const float* __restrict__ res, float* __restrict__ out,
    int M, int N, int KS)
{
  int i = blockIdx.x*256 + threadIdx.x;
  if (i >= N*M) return;
  float s = 0.f;
  for (int k=0;k<KS;++k) s += P[(size_t)k*((size_t)N*M) + i];
  int n = i / M, m = i - n*M;
  int b = n >> 10, l = n & 1023;
  size_t o = ((size_t)b*M + m)*LL + l;
  if (MODE==1) out[o] = s + bias[m];
  else         out[o] = s + res[o];
}

// -------- xp reduce both dirs: out flat (xdb contiguous) + bf16 dt-B pack --------
__global__ __launch_bounds__(256) void reducexp_k(
    const float* __restrict__ P, float* __restrict__ out, unsigned short* __restrict__ d16)
{
  int i = blockIdx.x*256 + threadIdx.x;      // < 262144 = 2*2048*64
  int dir = i >> 17, ii = i & 131071;
  float s = 0.f;
  #pragma unroll
  for (int k=0;k<4;++k) s += P[(size_t)(dir*4 + k)*131072 + ii];
  out[i] = s;
  int c = ii & 63;
  if (c < 32) d16[(size_t)(i>>6)*32 + c] = f2bu(s);
}

// -------- stem B': transpose + split3, k = tap*Cin + ci, pattern [hi|hi|lo] ------
__global__ __launch_bounds__(256) void ts_split3_k(
    const float* __restrict__ src, unsigned short* __restrict__ dst, int Cin)
{
  __shared__ float sx[32][35];
  int b = blockIdx.z;
  int l0 = blockIdx.x*32, ci0 = blockIdx.y*32;
  int tid = threadIdx.x;
  const float* sb = src + ((size_t)b*Cin + ci0)*LL;
  for (int idx = tid; idx < 32*34; idx += 256){
    int r = idx / 34, c = idx - r*34;
    int lp = l0 - 1 + c;
    sx[r][c] = (lp >= 0 && lp < LL) ? sb[(size_t)r*LL + lp] : 0.f;
  }
  __syncthreads();
  int K = 3*Cin, K3 = 9*Cin;
  int lr = tid >> 5, cl = tid & 31;
  #pragma unroll
  for (int p=0;p<4;++p){
    int l = lr + p*8;
    unsigned short* drow = dst + (size_t)(b*LL + l0 + l)*K3;
    #pragma unroll
    for (int tap=0; tap<3; ++tap){
      float v = sx[cl][l + tap];
      unsigned short hi = f2bu(v);
      unsigned short lo = f2bu(v - bu2f(hi));
      int kk = tap*Cin + ci0 + cl;
      drow[kk] = hi; drow[K + kk] = hi; drow[2*K + kk] = lo;
    }
  }
}

// -------- conv weights A': [Cout][3K] tap-major, pattern [hi|lo|hi] ------
__global__ __launch_bounds__(256) void wsplit3_conv_k(
    const float* __restrict__ w, unsigned short* __restrict__ dst, int Cout, int Cin)
{
  int i = blockIdx.x*256 + threadIdx.x;
  if (i >= Cout*Cin) return;
  int co = i / Cin, ci = i - co*Cin;
  int K = 3*Cin, K3 = 9*Cin;
  unsigned short* drow = dst + (size_t)co*K3;
  #pragma unroll
  for (int tap=0; tap<3; ++tap){
    float v = w[(size_t)(co*Cin + ci)*3 + tap];
    unsigned short hi = f2bu(v);
    unsigned short lo = f2bu(v - bu2f(hi));
    int kk = tap*Cin + ci;
    drow[kk] = hi; drow[K + kk] = lo; drow[2*K + kk] = hi;
  }
}

// -------- row-major split3, A-side [hi|lo|hi] --------
__global__ __launch_bounds__(256) void split3_k(
    const float* __restrict__ src, unsigned short* __restrict__ dst,
    int R, int K, int ld)
{
  int i = blockIdx.x*256 + threadIdx.x;
  int kq = K >> 2;
  if (i >= R*kq) return;
  int r = i / kq, k4 = (i - r*kq)*4;
  float4 v = *(const float4*)&src[(size_t)r*ld + k4];
  float vv[4] = {v.x, v.y, v.z, v.w};
  unsigned short hi[4], lo[4];
  #pragma unroll
  for (int j=0;j<4;++j){ hi[j]=f2bu(vv[j]); lo[j]=f2bu(vv[j]-bu2f(hi[j])); }
  unsigned short* d0 = dst + (size_t)r*3*K + k4;
  ushort4 h4 = make_ushort4(hi[0],hi[1],hi[2],hi[3]);
  ushort4 l4 = make_ushort4(lo[0],lo[1],lo[2],lo[3]);
  *(ushort4*)d0 = h4;
  *(ushort4*)(d0 + K)   = l4;
  *(ushort4*)(d0 + 2*K) = h4;
}

// -------- plain hi split (bf16 cast) --------
__global__ __launch_bounds__(256) void split1_k(
    const float* __restrict__ src, unsigned short* __restrict__ dst,
    int R, int K, int ld, int k0)
{
  int i = blockIdx.x*256 + threadIdx.x;
  int kq = K >> 2;
  if (i >= R*kq) return;
  int r = i / kq, k4 = (i - r*kq)*4;
  float4 v = *(const float4*)&src[(size_t)r*ld + k0 + k4];
  *(ushort4*)(dst + (size_t)r*K + k4) =
      make_ushort4(f2bu(v.x), f2bu(v.y), f2bu(v.z), f2bu(v.w));
}

// -------- dual-source plain split (both directions in one launch) --------
__global__ __launch_bounds__(256) void split1x2_k(
    const float* __restrict__ s0, const float* __restrict__ s1,
    unsigned short* __restrict__ d, int R, int K, int dstr)
{
  int i = blockIdx.x*256 + threadIdx.x;
  int kq = K >> 2, tot = R*kq;
  if (i >= 2*tot) return;
  int dir = i >= tot, ii = i - dir*tot;
  const float* src = dir ? s1 : s0;
  int r = ii / kq, k4 = (ii - r*kq)*4;
  float4 v = *(const float4*)&src[(size_t)r*K + k4];
  *(ushort4*)(d + (size_t)dir*dstr + (size_t)r*K + k4) =
      make_ushort4(f2bu(v.x), f2bu(v.y), f2bu(v.z), f2bu(v.w));
}

// -------- out-proj B: hi((y0+y1)*silu(z)), z transposed from xz --------
__global__ __launch_bounds__(256) void gated_split_k(
    const float* __restrict__ y0, const float* __restrict__ y1,
    const float* __restrict__ xz, unsigned short* __restrict__ dst)
{
  __shared__ float sz[32][33];
  int b = blockIdx.z;
  int l0 = blockIdx.x*32, d0 = blockIdx.y*32;
  int tid = threadIdx.x;
  const float* zb = xz + ((size_t)b*2048 + 1024 + d0)*LL + l0;
  for (int idx = tid; idx < 1024; idx += 256){
    int r = idx >> 5, c = idx & 31;
    sz[r][c] = zb[(size_t)r*LL + c];
  }
  __syncthreads();
  int lr = tid >> 5, dd = tid & 31;
  #pragma unroll
  for (int p=0;p<4;++p){
    int l = lr + p*8;
    size_t n = (size_t)b*LL + l0 + l;
    float zv = sz[dd][l];
    float y = y0[n*1024 + d0 + dd] + y1[n*1024 + d0 + dd];
    dst[n*1024 + d0 + dd] = f2bu(y * (zv * sigmoidf_(zv)));
  }
}

// ---------------- bf16 MFMA GEMM (m97 structure): C[n][m] = sum_k B[n][k]*A[m][k] --
// global_load_lds 16B staging, linear LDS, XOR-swizzle via pre-swizzled global src.
// BN=64: 4 waves 2x2 (wm=w&1), wave tile (BM/2)x32. BN=128: wm=w>>1, tile (BM/2)x64.
// DUAL: dir = blockIdx.z/(gridDim.z/2); A/B/bias/C per-dir via strides.
// EPI 0: fp32 partials P[z][n*M+m]; EPI 1: C[(b*M+m)*LL+l]; EPI 2: bf16 softplus
template<int BM, int BN, int BK, int EPI, int DUAL>
__global__ __launch_bounds__(256) void gemm_bf3(
    const unsigned short* __restrict__ A, const unsigned short* __restrict__ B,
    const float* __restrict__ bias, const float* __restrict__ bias2,
    void* __restrict__ Cv, int M, int N, int K3,
    int AStr, int BStr, long CStr)
{
  constexpr int RB = 2*BK;
  constexpr int RPL = 1024/RB;
  constexpr int ALD = BM/RPL;
  constexpr int BLD = BN/RPL;
  constexpr int NL = ALD + BLD;
  constexpr int FM = BM/32;
  constexpr int WCOL = BN/2;
  constexpr int FN = WCOL/16;
  constexpr int KH = BK/32;
  __shared__ __align__(16) char smem[(BM+BN)*RB];
  char* As = smem;
  char* Bs = smem + BM*RB;
  int tid = threadIdx.x;
  int w = tid >> 6, lane = tid & 63;
  int wm, wn;
  if (BN == 128){ wm = w>>1; wn = w&1; }
  else          { wm = w&1;  wn = w>>1; }
  int n0 = blockIdx.x*BN, m0 = blockIdx.y*BM;

  int zz = blockIdx.z, nz = gridDim.z, dir = 0;
  if (DUAL){
    int hz = nz >> 1;
    dir = zz / hz; zz -= dir*hz; nz = hz;
    A += (size_t)dir*AStr; B += (size_t)dir*BStr;
    if (dir && bias2) bias = bias2;
  }
  int kper = K3 / nz;
  int kbeg = zz * kper;

  int lr, sc;
  if (BK == 64){ lr = lane>>3; sc = (lane&7) ^ lr; }
  else         { lr = lane>>2; sc = (lane&3) ^ ((lr>>1)&3); }
  size_t lsrc = (size_t)lr*K3 + sc*8;

  f32x4 acc[FM][FN];
  #pragma unroll
  for (int i=0;i<FM;++i)
    #pragma unroll
    for (int j=0;j<FN;++j) acc[i][j] = (f32x4){0,0,0,0};

  int r16 = lane & 15, g4 = lane >> 4;
  for (int k = kbeg; k < kbeg + kper; k += BK){
    for (int j = w; j < NL; j += 4){
      if (j < ALD){
        gl2lds16(A + (size_t)(m0 + j*RPL)*K3 + k + lsrc, As + j*(RPL*RB));
      } else {
        int jb = j - ALD;
        gl2lds16(B + (size_t)(n0 + jb*RPL)*K3 + k + lsrc, Bs + jb*(RPL*RB));
      }
    }
    __syncthreads();
    #pragma unroll
    for (int kh=0; kh<KH; ++kh){
      int c = kh*4 + g4;
      short8_t bf[FN];
      #pragma unroll
      for (int j2=0;j2<FN;++j2){
        int rb = wn*WCOL + j2*16 + r16;
        int pb = (BK==64) ? (c ^ (rb&7)) : (c ^ ((rb>>1)&3));
        bf[j2] = *(short8_t*)&Bs[rb*RB + pb*16];
      }
      #pragma unroll
      for (int i2=0;i2<FM;++i2){
        int ra = wm*(BM/2) + i2*16 + r16;
        int pa = (BK==64) ? (c ^ (ra&7)) : (c ^ ((ra>>1)&3));
        short8_t af = *(short8_t*)&As[ra*RB + pa*16];
        #pragma unroll
        for (int j2=0;j2<FN;++j2)
          acc[i2][j2] = __builtin_amdgcn_mfma_f32_16x16x32_bf16(af, bf[j2], acc[i2][j2], 0,0,0);
      }
    }
    __syncthreads();
  }
  #pragma unroll
  for (int i2=0;i2<FM;++i2){
    #pragma unroll
    for (int j2=0;j2<FN;++j2){
      #pragma unroll
      for (int r=0;r<4;++r){
        int m = m0 + wm*(BM/2) + i2*16 + (g4*4 + r);
        int n = n0 + wn*WCOL + j2*16 + r16;
        float v = acc[i2][j2][r];
        if (EPI==0){
          ((float*)Cv)[(size_t)blockIdx.z*((size_t)N*M) + (size_t)n*M + m] = v;
        } else if (EPI==1){
          int b = n>>10, l = n&1023;
          ((float*)Cv)[((size_t)b*M + m)*LL + l] = v;
        } else {
          float xv = v + bias[m];
          float sp = (xv > 20.f) ? xv : log1pf(__expf(xv));
          (((unsigned short*)Cv) + (size_t)dir*CStr)[(size_t)n*M + m] = f2bu(sp);
        }
      }
    }
  }
}

// -------- causal depthwise conv k4 + SiLU, bf16 transposed out; both dirs ------
__global__ __launch_bounds__(256) void dwconv_k(
    const float* __restrict__ xz, const float* __restrict__ cw0,
    const float* __restrict__ cb0, const float* __restrict__ cw1,
    const float* __restrict__ cb1, unsigned short* __restrict__ outT0)
{
  __shared__ float sx[64][73];
  int zc = blockIdx.z;
  int b = zc & 1, rev = zc >> 1;
  const float* cw = rev ? cw1 : cw0;
  const float* cb = rev ? cb1 : cb0;
  unsigned short* outT = outT0 + (size_t)rev*2097152;
  int l0 = blockIdx.x * 64;
  int d0 = blockIdx.y * 64;
  int tid = threadIdx.x;
  const float* base = xz + ((size_t)b*2048 + d0)*LL;
  for (int idx = tid; idx < 64*67; idx += 256) {
    int r = idx / 67, i = idx - r*67;
    int lp = l0 - 3 + i;
    float v = 0.f;
    if (lp >= 0) v = base[(size_t)r*LL + (rev ? (LL-1-lp) : lp)];
    sx[r][i] = v;
  }
  __syncthreads();
  int dof = tid & 63;
  int lq = tid >> 6;
  int d = d0 + dof;
  float4 w4 = *(const float4*)(cw + (size_t)d*4);
  float bv = cb[d];
  unsigned short* orow = outT + (size_t)b*LL*1024 + d;
  #pragma unroll
  for (int j=0;j<16;++j){
    int lr = lq + j*4;
    float acc = bv + w4.x*sx[dof][lr] + w4.y*sx[dof][lr+1]
                   + w4.z*sx[dof][lr+2] + w4.w*sx[dof][lr+3];
    orow[(size_t)(l0+lr)*1024] = f2bu(acc * sigmoidf_(acc));
  }
}

// ================= chunked selective scan (lane-owns-channel) =================
__global__ __launch_bounds__(256) void scan1_k(
    const unsigned short* __restrict__ de0, const unsigned short* __restrict__ de1,
    const unsigned short* __restrict__ u0, const unsigned short* __restrict__ u1,
    const float* __restrict__ xd0, const float* __restrict__ xd1,
    const float* __restrict__ al0, const float* __restrict__ al1,
    float* __restrict__ Pbuf, float* __restrict__ Sbuf)
{
  __shared__ float sBC[CS][32];
  int zc = blockIdx.z, dir = zc>>1, b = zc&1;
  const unsigned short* de = dir? de1:de0;
  const unsigned short* uT = dir? u1:u0;
  const float* xd = dir? xd1:xd0;
  const float* al = dir? al1:al0;
  int t = threadIdx.x;
  int d = blockIdx.x*128 + (t>>1);
  int sh = (t&1)*8;
  int l0 = blockIdx.y*CS;
  size_t nrow = (size_t)b*1024 + l0;
  for (int idx = t; idx < CS*32; idx += 256){
    int r = idx >> 5, c = idx & 31;
    sBC[r][c] = xd[(nrow + r)*64 + 32 + c];
  }
  __syncthreads();
  float A[8], h[8], P[8];
  #pragma unroll
  for (int j=0;j<8;++j){ A[j] = -expf(al[d*16 + sh + j]); h[j]=0.f; P[j]=1.f; }
  const unsigned short* dep = de + nrow*1024 + d;
  const unsigned short* up  = uT + nrow*1024 + d;
  for (int l=0; l<CS; ++l){
    float dv = bu2f(dep[(size_t)l*1024]);
    float uv = bu2f(up[(size_t)l*1024]);
    float du = dv*uv;
    #pragma unroll
    for (int j=0;j<8;++j){
      float a = __expf(dv*A[j]);
      h[j] = a*h[j] + du*sBC[l][sh+j];
      P[j] *= a;
    }
  }
  size_t sb = (size_t)blockIdx.y*65536 + (size_t)(zc*1024 + d)*16 + sh;
  *(float4*)&Pbuf[sb]   = make_float4(P[0],P[1],P[2],P[3]);
  *(float4*)&Pbuf[sb+4] = make_float4(P[4],P[5],P[6],P[7]);
  *(float4*)&Sbuf[sb]   = make_float4(h[0],h[1],h[2],h[3]);
  *(float4*)&Sbuf[sb+4] = make_float4(h[4],h[5],h[6],h[7]);
}

__global__ __launch_bounds__(256) void scan2_k(
    const float* __restrict__ Pbuf, const float* __restrict__ Sbuf,
    float* __restrict__ Hbuf)
{
  int seq = blockIdx.x*256 + threadIdx.x;
  float H = 0.f;
  #pragma unroll
  for (int cch=0; cch<NC; ++cch){
    Hbuf[(size_t)cch*65536 + seq] = H;
    H = Pbuf[(size_t)cch*65536 + seq]*H + Sbuf[(size_t)cch*65536 + seq];
  }
}

__global__ __launch_bounds__(256) void scan3_k(
    const unsigned short* __restrict__ de0, const unsigned short* __restrict__ de1,
    const unsigned short* __restrict__ u0, const unsigned short* __restrict__ u1,
    const float* __restrict__ xd0, const float* __restrict__ xd1,
    const float* __restrict__ al0, const float* __restrict__ al1,
    const float* __restrict__ dd0, const float* __restrict__ dd1,
    const float* __restrict__ Hbuf,
    float* __restrict__ y0, float* __restrict__ y1)
{
  __shared__ float sBC[CS][32];
  int zc = blockIdx.z, dir = zc>>1, b = zc&1;
  const unsigned short* de = dir? de1:de0;
  const unsigned short* uT = dir? u1:u0;
  const float* xd = dir? xd1:xd0;
  const float* al = dir? al1:al0;
  const float* DD = dir? dd1:dd0;
  float* y = dir? y1:y0;
  int t = threadIdx.x;
  int d = blockIdx.x*128 + (t>>1);
  int sh = (t&1)*8;
  int l0 = blockIdx.y*CS;
  size_t nrow = (size_t)b*1024 + l0;
  for (int idx = t; idx < CS*32; idx += 256){
    int r = idx >> 5, c = idx & 31;
    sBC[r][c] = xd[(nrow + r)*64 + 32 + c];
  }
  __syncthreads();
  float A[8], h[8];
  size_t sb = (size_t)blockIdx.y*65536 + (size_t)(zc*1024 + d)*16 + sh;
  float4 h03 = *(const float4*)&Hbuf[sb];
  float4 h47 = *(const float4*)&Hbuf[sb+4];
  h[0]=h03.x; h[1]=h03.y; h[2]=h03.z; h[3]=h03.w;
  h[4]=h47.x; h[5]=h47.y; h[6]=h47.z; h[7]=h47.w;
  #pragma unroll
  for (int j=0;j<8;++j) A[j] = -expf(al[d*16 + sh + j]);
  float Dd = DD[d];
  const unsigned short* dep = de + nrow*1024 + d;
  const unsigned short* up  = uT + nrow*1024 + d;
  float* yb = y + (size_t)b*LL*1024 + d;
  for (int l=0; l<CS; ++l){
    float dv = bu2f(dep[(size_t)l*1024]);
    float uv = bu2f(up[(size_t)l*1024]);
    float du = dv*uv;
    float pa = 0.f;
    #pragma unroll
    for (int j=0;j<8;++j){
      float a = __expf(dv*A[j]);
      h[j] = a*h[j] + du*sBC[l][sh+j];
      pa += h[j]*sBC[l][16+sh+j];
    }
    pa += __shfl_xor(pa, 1);
    if ((t&1)==0){
      int lo = dir ? (1023 - l0 - l) : (l0 + l);
      yb[(size_t)lo*1024] = pa + uv*Dd;
    }
  }
}

extern "C" void kernel_launch(void* const* d_in, const int* in_sizes, int n_in,
                              void* d_out, int out_size, void* d_ws, size_t ws_size,
                              hipStream_t stream)
{
  const float* x   = (const float*)d_in[0];
  const float* c1w = (const float*)d_in[1];  const float* c1b = (const float*)d_in[2];
  const float* g1g = (const float*)d_in[3];  const float* g1b = (const float*)d_in[4];
  const float* c2w = (const float*)d_in[5];  const float* c2b = (const float*)d_in[6];
  const float* g2g = (const float*)d_in[7];  const float* g2b = (const float*)d_in[8];
  const float* c3w = (const float*)d_in[9];  const float* c3b = (const float*)d_in[10];
  const float* g3g = (const float*)d_in[11]; const float* g3b = (const float*)d_in[12];
  const float* lng = (const float*)d_in[13]; const float* lnb = (const float*)d_in[14];
  const float* ipw = (const float*)d_in[15]; const float* opw = (const float*)d_in[16];
  const float* cvw[2]  = {(const float*)d_in[17], (const float*)d_in[24]};
  const float* cvb[2]  = {(const float*)d_in[18], (const float*)d_in[25]};
  const float* xpw[2]  = {(const float*)d_in[19], (const float*)d_in[26]};
  const float* dtw[2]  = {(const float*)d_in[20], (const float*)d_in[27]};
  const float* dtb[2]  = {(const float*)d_in[21], (const float*)d_in[28]};
  const float* alog[2] = {(const float*)d_in[22], (const float*)d_in[29]};
  const float* Dp[2]   = {(const float*)d_in[23], (const float*)d_in[30]};

  float* ws = (float*)d_ws;
  // ---- workspace map (floats) ----
  float* h3  = ws;                         // [0, 1048576) residual
  float* h1  = ws + 1048576;               // stem; later xdb (flat 262144)
  float* h2  = ws + 1310720;               // stem
  float* Hb  = ws + 1835008;               // scan chunk-start states (1048576)
  float* xzb = ws + 2883584;               // [.., 7077888) xz; x-halves later Pb/Sb
  unsigned short* Wb = (unsigned short*)(ws + 7077888);   // A' splits region
  unsigned short* Bsb = (unsigned short*)(ws + 8650752);  // B' splits region
  float* yy0 = ws + 11796480;
  float* yy1 = ws + 13893632;
  float* PART = ws + 15990784;             // partials; later dl (bf16)
  unsigned short* xcv[2] = { (unsigned short*)(ws + 18087936),
                             (unsigned short*)(ws + 18087936) + 2097152 };
  // aliases
  float* xdb[2] = { ws + 1048576, ws + 1179648 };          // flat contiguous
  unsigned short* dl[2] = { (unsigned short*)PART, (unsigned short*)PART + 2097152 };
  float* Pb = ws + 2883584;                // b0 x-half (dead after dwconv)
  float* Sb = ws + 4980736;                // b1 x-half
  float* pxp = ws + 8650752;               // 8 x 131072 partials (Bsb region, dead)
  unsigned short* dtB = (unsigned short*)(ws + 9699328);   // after pxp: 4096x32 bf16
  unsigned short* WbXp = Wb;               // 2 x 64x1024 bf16
  unsigned short* WbDt = Wb + 131072;      // 2 x 1024x32 bf16
  float* out = (float*)d_out;

  // ================= CNN stem (split-bf16 MFMA) =================
  ts_split3_k<<<dim3(32,24,2), 256, 0, stream>>>(x, Bsb, 768);
  wsplit3_conv_k<<<384, 256, 0, stream>>>(c1w, Wb, 128, 768);
  gemm_bf3<64,64,64,0,0><<<dim3(32,2,4), 256, 0, stream>>>(
      Wb, Bsb, nullptr, nullptr, PART, 128, 2048, 6912, 0,0,0);
  reduceK_k<1><<<1024, 256, 0, stream>>>(PART, c1b, nullptr, h1, 128, 2048, 4);
  gn_relu_k<<<64, 256, 0, stream>>>(h1, g1g, g1b, 128, 4);

  ts_split3_k<<<dim3(32,4,2), 256, 0, stream>>>(h1, Bsb, 128);
  wsplit3_conv_k<<<128, 256, 0, stream>>>(c2w, Wb, 256, 128);
  gemm_bf3<64,64,64,0,0><<<dim3(32,4,2), 256, 0, stream>>>(
      Wb, Bsb, nullptr, nullptr, PART, 256, 2048, 1152, 0,0,0);
  reduceK_k<1><<<2048, 256, 0, stream>>>(PART, c2b, nullptr, h2, 256, 2048, 2);
  gn_relu_k<<<64, 256, 0, stream>>>(h2, g2g, g2b, 256, 8);

  ts_split3_k<<<dim3(32,8,2), 256, 0, stream>>>(h2, Bsb, 256);
  wsplit3_conv_k<<<512, 256, 0, stream>>>(c3w, Wb, 512, 256);
  gemm_bf3<128,64,64,0,0><<<dim3(32,4,2), 256, 0, stream>>>(
      Wb, Bsb, nullptr, nullptr, PART, 512, 2048, 2304, 0,0,0);
  reduceK_k<1><<<4096, 256, 0, stream>>>(PART, c3b, nullptr, h3, 512, 2048, 2);
  gn_relu_k<<<64, 256, 0, stream>>>(h3, g3g, g3b, 512, 16);

  // ================= fused LN+split -> in_proj (128x128 tile) =================
  ln_split_k<<<2048, 64, 0, stream>>>(h3, lng, lnb, Bsb);
  split3_k<<<1024, 256, 0, stream>>>(ipw, Wb, 2048, 512, 512);
  gemm_bf3<128,128,64,1,0><<<dim3(16,16,1), 256, 0, stream>>>(
      Wb, Bsb, nullptr, nullptr, xzb, 2048, 2048, 1536, 0,0,0);

  // ================= per-direction conv/proj/delta (dual launches) =============
  dwconv_k<<<dim3(16,16,4), 256, 0, stream>>>(xzb, cvw[0], cvb[0], cvw[1], cvb[1], xcv[0]);
  split1x2_k<<<128, 256, 0, stream>>>(xpw[0], xpw[1], WbXp, 64, 1024, 65536);
  gemm_bf3<64,64,64,0,1><<<dim3(32,1,8), 256, 0, stream>>>(
      WbXp, xcv[0], nullptr, nullptr, pxp, 64, 2048, 1024, 65536, 2097152, 0);
  reducexp_k<<<1024, 256, 0, stream>>>(pxp, xdb[0], dtB);
  split1x2_k<<<64, 256, 0, stream>>>(dtw[0], dtw[1], WbDt, 1024, 32, 32768);
  gemm_bf3<128,64,32,2,1><<<dim3(32,8,2), 256, 0, stream>>>(
      WbDt, dtB, dtb[0], dtb[1], dl[0], 1024, 2048, 32, 32768, 65536, 2097152);

  // ================= chunked selective scan =================
  scan1_k<<<dim3(8,NC,4), 256, 0, stream>>>(
      dl[0], dl[1], xcv[0], xcv[1], xdb[0], xdb[1], alog[0], alog[1], Pb, Sb);
  scan2_k<<<256, 256, 0, stream>>>(Pb, Sb, Hb);
  scan3_k<<<dim3(8,NC,4), 256, 0, stream>>>(
      dl[0], dl[1], xcv[0], xcv[1], xdb[0], xdb[1], alog[0], alog[1],
      Dp[0], Dp[1], Hb, yy0, yy1);

  // ================= gate + out_proj (bf16 MFMA) + residual =================
  gated_split_k<<<dim3(32,32,2), 256, 0, stream>>>(yy0, yy1, xzb, Bsb);
  split1_k<<<512, 256, 0, stream>>>(opw, Wb, 512, 1024, 1024, 0);
  gemm_bf3<128,64,64,0,0><<<dim3(32,4,2), 256, 0, stream>>>(
      Wb, Bsb, nullptr, nullptr, PART, 512, 2048, 1024, 0,0,0);
  reduceK_k<2><<<4096, 256, 0, stream>>>(PART, nullptr, h3, out, 512, 2048, 2);
}

// Round 10
// 439.640 us; speedup vs baseline: 2.3442x; 1.0478x over previous
//
#include <hip/hip_runtime.h>
#include <hip/hip_bf16.h>
#include <math.h>

#define LL 1024
#define NC 16
#define CS 64

typedef __attribute__((ext_vector_type(8))) short short8_t;
typedef __attribute__((ext_vector_type(4))) float f32x4;

__device__ __forceinline__ float sigmoidf_(float x){ return 1.f/(1.f+__expf(-x)); }
__device__ __forceinline__ unsigned short f2bu(float x){
  unsigned int u = __float_as_uint(x);
  unsigned int r = (u + 0x7fffu + ((u>>16)&1u)) >> 16;
  return (unsigned short)r;
}
__device__ __forceinline__ float bu2f(unsigned short u){
  return __uint_as_float(((unsigned int)u)<<16);
}
__device__ __forceinline__ void gl2lds16(const void* g, void* l){
  __builtin_amdgcn_global_load_lds(
      (const __attribute__((address_space(1))) unsigned int*)g,
      (__attribute__((address_space(3))) unsigned int*)l, 16, 0, 0);
}

// ---------------- GroupNorm(32) + ReLU, in place ----------------
__global__ __launch_bounds__(256) void gn_relu_k(
    float* __restrict__ io, const float* __restrict__ g, const float* __restrict__ bt,
    int C, int Cg)
{
  int b = blockIdx.x >> 5;
  int grp = blockIdx.x & 31;
  int n = Cg * LL;
  float* p = io + ((size_t)b*C + (size_t)grp*Cg)*LL;
  int tid = threadIdx.x;
  float s=0.f, s2=0.f;
  for (int i=tid; i<n; i+=256){ float v=p[i]; s+=v; s2+=v*v; }
  __shared__ float red[10];
  #pragma unroll
  for (int off=32; off; off>>=1){ s+=__shfl_down(s,off); s2+=__shfl_down(s2,off); }
  if ((tid&63)==0){ red[tid>>6]=s; red[4+(tid>>6)]=s2; }
  __syncthreads();
  if (tid==0){
    float S=red[0]+red[1]+red[2]+red[3];
    float S2=red[4]+red[5]+red[6]+red[7];
    float mean = S/(float)n;
    float var = S2/(float)n - mean*mean;
    red[8]=mean; red[9]=rsqrtf(var+1e-5f);
  }
  __syncthreads();
  float mean=red[8], rstd=red[9];
  const float* gp = g + grp*Cg;
  const float* bp = bt + grp*Cg;
  for (int i=tid; i<n; i+=256){
    int co = i >> 10;
    float v = (p[i]-mean)*rstd*gp[co] + bp[co];
    p[i] = fmaxf(v, 0.f);
  }
}

// ------- fused LayerNorm + B-side split3 ([hi|hi|lo]) over C=512 per (b,l) -------
__global__ __launch_bounds__(64) void ln_split_k(
    const float* __restrict__ h, const float* __restrict__ g, const float* __restrict__ bt,
    unsigned short* __restrict__ dst)
{
  int bl = blockIdx.x;
  int b = bl >> 10, l = bl & 1023;
  int lane = threadIdx.x;
  const float* base = h + (size_t)b*512*LL + l;
  float v[8]; float s=0.f, s2=0.f;
  #pragma unroll
  for (int j=0;j<8;++j){ v[j] = base[(size_t)(lane*8 + j)*LL]; s+=v[j]; s2+=v[j]*v[j]; }
  #pragma unroll
  for (int off=32; off; off>>=1){ s+=__shfl_xor(s,off); s2+=__shfl_xor(s2,off); }
  float mean = s*(1.f/512.f);
  float rstd = rsqrtf(s2*(1.f/512.f) - mean*mean + 1e-5f);
  unsigned short hi[8], lo[8];
  #pragma unroll
  for (int j=0;j<8;++j){
    int c = lane*8 + j;
    float f = (v[j]-mean)*rstd*g[c] + bt[c];
    hi[j] = f2bu(f); lo[j] = f2bu(f - bu2f(hi[j]));
  }
  unsigned short* row = dst + (size_t)bl*1536 + lane*8;
  *(ushort4*)&row[0] = make_ushort4(hi[0],hi[1],hi[2],hi[3]);
  *(ushort4*)&row[4] = make_ushort4(hi[4],hi[5],hi[6],hi[7]);
  *(ushort4*)&row[512] = make_ushort4(hi[0],hi[1],hi[2],hi[3]);
  *(ushort4*)&row[516] = make_ushort4(hi[4],hi[5],hi[6],hi[7]);
  *(ushort4*)&row[1024] = make_ushort4(lo[0],lo[1],lo[2],lo[3]);
  *(ushort4*)&row[1028] = make_ushort4(lo[4],lo[5],lo[6],lo[7]);
}

// ---------------- split-K reduce: MODE 1 bias, MODE 2 residual ----------------
template<int MODE>
__global__ __launch_bounds__(256) void reduceK_k(
    const float* __restrict__ P, const float* __restrict__ bias,
    const float* __restrict__ res, float* __restrict__ out,
    int M, int N, int KS)
{
  int i = blockIdx.x*256 + threadIdx.x;
  if (i >= N*M) return;
  float s = 0.f;
  for (int k=0;k<KS;++k) s += P[(size_t)k*((size_t)N*M) + i];
  int n = i / M, m = i - n*M;
  int b = n >> 10, l = n & 1023;
  size_t o = ((size_t)b*M + m)*LL + l;
  if (MODE==1) out[o] = s + bias[m];
  else         out[o] = s + res[o];
}

// -------- xp reduce both dirs (8 slices each) + bf16 dt-B pack --------
__global__ __launch_bounds__(256) void reducexp_k(
    const float* __restrict__ P, float* __restrict__ out, unsigned short* __restrict__ d16)
{
  int i = blockIdx.x*256 + threadIdx.x;      // < 262144 = 2*2048*64
  int dir = i >> 17, ii = i & 131071;
  float s = 0.f;
  #pragma unroll
  for (int k=0;k<8;++k) s += P[(size_t)(dir*8 + k)*131072 + ii];
  out[i] = s;
  int c = ii & 63;
  if (c < 32) d16[(size_t)(i>>6)*32 + c] = f2bu(s);
}

// -------- stem B': transpose + split3, k = tap*Cin + ci, pattern [hi|hi|lo] ------
__global__ __launch_bounds__(256) void ts_split3_k(
    const float* __restrict__ src, unsigned short* __restrict__ dst, int Cin)
{
  __shared__ float sx[32][35];
  int b = blockIdx.z;
  int l0 = blockIdx.x*32, ci0 = blockIdx.y*32;
  int tid = threadIdx.x;
  const float* sb = src + ((size_t)b*Cin + ci0)*LL;
  for (int idx = tid; idx < 32*34; idx += 256){
    int r = idx / 34, c = idx - r*34;
    int lp = l0 - 1 + c;
    sx[r][c] = (lp >= 0 && lp < LL) ? sb[(size_t)r*LL + lp] : 0.f;
  }
  __syncthreads();
  int K = 3*Cin, K3 = 9*Cin;
  int lr = tid >> 5, cl = tid & 31;
  #pragma unroll
  for (int p=0;p<4;++p){
    int l = lr + p*8;
    unsigned short* drow = dst + (size_t)(b*LL + l0 + l)*K3;
    #pragma unroll
    for (int tap=0; tap<3; ++tap){
      float v = sx[cl][l + tap];
      unsigned short hi = f2bu(v);
      unsigned short lo = f2bu(v - bu2f(hi));
      int kk = tap*Cin + ci0 + cl;
      drow[kk] = hi; drow[K + kk] = hi; drow[2*K + kk] = lo;
    }
  }
}

// -------- conv weights A': [Cout][3K] tap-major, pattern [hi|lo|hi] ------
__global__ __launch_bounds__(256) void wsplit3_conv_k(
    const float* __restrict__ w, unsigned short* __restrict__ dst, int Cout, int Cin)
{
  int i = blockIdx.x*256 + threadIdx.x;
  if (i >= Cout*Cin) return;
  int co = i / Cin, ci = i - co*Cin;
  int K = 3*Cin, K3 = 9*Cin;
  unsigned short* drow = dst + (size_t)co*K3;
  #pragma unroll
  for (int tap=0; tap<3; ++tap){
    float v = w[(size_t)(co*Cin + ci)*3 + tap];
    unsigned short hi = f2bu(v);
    unsigned short lo = f2bu(v - bu2f(hi));
    int kk = tap*Cin + ci;
    drow[kk] = hi; drow[K + kk] = lo; drow[2*K + kk] = hi;
  }
}

// -------- row-major split3, A-side [hi|lo|hi] --------
__global__ __launch_bounds__(256) void split3_k(
    const float* __restrict__ src, unsigned short* __restrict__ dst,
    int R, int K, int ld)
{
  int i = blockIdx.x*256 + threadIdx.x;
  int kq = K >> 2;
  if (i >= R*kq) return;
  int r = i / kq, k4 = (i - r*kq)*4;
  float4 v = *(const float4*)&src[(size_t)r*ld + k4];
  float vv[4] = {v.x, v.y, v.z, v.w};
  unsigned short hi[4], lo[4];
  #pragma unroll
  for (int j=0;j<4;++j){ hi[j]=f2bu(vv[j]); lo[j]=f2bu(vv[j]-bu2f(hi[j])); }
  unsigned short* d0 = dst + (size_t)r*3*K + k4;
  ushort4 h4 = make_ushort4(hi[0],hi[1],hi[2],hi[3]);
  ushort4 l4 = make_ushort4(lo[0],lo[1],lo[2],lo[3]);
  *(ushort4*)d0 = h4;
  *(ushort4*)(d0 + K)   = l4;
  *(ushort4*)(d0 + 2*K) = h4;
}

// -------- plain hi split (bf16 cast) --------
__global__ __launch_bounds__(256) void split1_k(
    const float* __restrict__ src, unsigned short* __restrict__ dst,
    int R, int K, int ld, int k0)
{
  int i = blockIdx.x*256 + threadIdx.x;
  int kq = K >> 2;
  if (i >= R*kq) return;
  int r = i / kq, k4 = (i - r*kq)*4;
  float4 v = *(const float4*)&src[(size_t)r*ld + k0 + k4];
  *(ushort4*)(dst + (size_t)r*K + k4) =
      make_ushort4(f2bu(v.x), f2bu(v.y), f2bu(v.z), f2bu(v.w));
}

// -------- dual-source plain split (both directions in one launch) --------
__global__ __launch_bounds__(256) void split1x2_k(
    const float* __restrict__ s0, const float* __restrict__ s1,
    unsigned short* __restrict__ d, int R, int K, int dstr)
{
  int i = blockIdx.x*256 + threadIdx.x;
  int kq = K >> 2, tot = R*kq;
  if (i >= 2*tot) return;
  int dir = i >= tot, ii = i - dir*tot;
  const float* src = dir ? s1 : s0;
  int r = ii / kq, k4 = (ii - r*kq)*4;
  float4 v = *(const float4*)&src[(size_t)r*K + k4];
  *(ushort4*)(d + (size_t)dir*dstr + (size_t)r*K + k4) =
      make_ushort4(f2bu(v.x), f2bu(v.y), f2bu(v.z), f2bu(v.w));
}

// -------- out-proj B: hi((y0+y1)*silu(z)), z transposed from xz --------
__global__ __launch_bounds__(256) void gated_split_k(
    const float* __restrict__ y0, const float* __restrict__ y1,
    const float* __restrict__ xz, unsigned short* __restrict__ dst)
{
  __shared__ float sz[32][33];
  int b = blockIdx.z;
  int l0 = blockIdx.x*32, d0 = blockIdx.y*32;
  int tid = threadIdx.x;
  const float* zb = xz + ((size_t)b*2048 + 1024 + d0)*LL + l0;
  for (int idx = tid; idx < 1024; idx += 256){
    int r = idx >> 5, c = idx & 31;
    sz[r][c] = zb[(size_t)r*LL + c];
  }
  __syncthreads();
  int lr = tid >> 5, dd = tid & 31;
  #pragma unroll
  for (int p=0;p<4;++p){
    int l = lr + p*8;
    size_t n = (size_t)b*LL + l0 + l;
    float zv = sz[dd][l];
    float y = y0[n*1024 + d0 + dd] + y1[n*1024 + d0 + dd];
    dst[n*1024 + d0 + dd] = f2bu(y * (zv * sigmoidf_(zv)));
  }
}

// ---------------- bf16 MFMA GEMM (m97 structure): C[n][m] = sum_k B[n][k]*A[m][k] --
// global_load_lds 16B staging, linear LDS, XOR-swizzle via pre-swizzled global src.
// BN=64: 4 waves 2x2 (wm=w&1), wave tile (BM/2)x32. BN=128: wm=w>>1, tile (BM/2)x64.
// DUAL: dir = blockIdx.z/(gridDim.z/2); A/B/bias/C per-dir via strides.
// EPI 0: fp32 partials P[z][n*M+m]; EPI 1: C[(b*M+m)*LL+l]; EPI 2: bf16 softplus
template<int BM, int BN, int BK, int EPI, int DUAL>
__global__ __launch_bounds__(256) void gemm_bf3(
    const unsigned short* __restrict__ A, const unsigned short* __restrict__ B,
    const float* __restrict__ bias, const float* __restrict__ bias2,
    void* __restrict__ Cv, int M, int N, int K3,
    int AStr, int BStr, long CStr)
{
  constexpr int RB = 2*BK;
  constexpr int RPL = 1024/RB;
  constexpr int ALD = BM/RPL;
  constexpr int BLD = BN/RPL;
  constexpr int NL = ALD + BLD;
  constexpr int FM = BM/32;
  constexpr int WCOL = BN/2;
  constexpr int FN = WCOL/16;
  constexpr int KH = BK/32;
  __shared__ __align__(16) char smem[(BM+BN)*RB];
  char* As = smem;
  char* Bs = smem + BM*RB;
  int tid = threadIdx.x;
  int w = tid >> 6, lane = tid & 63;
  int wm, wn;
  if (BN == 128){ wm = w>>1; wn = w&1; }
  else          { wm = w&1;  wn = w>>1; }
  int n0 = blockIdx.x*BN, m0 = blockIdx.y*BM;

  int zz = blockIdx.z, nz = gridDim.z, dir = 0;
  if (DUAL){
    int hz = nz >> 1;
    dir = zz / hz; zz -= dir*hz; nz = hz;
    A += (size_t)dir*AStr; B += (size_t)dir*BStr;
    if (dir && bias2) bias = bias2;
  }
  int kper = K3 / nz;
  int kbeg = zz * kper;

  int lr, sc;
  if (BK == 64){ lr = lane>>3; sc = (lane&7) ^ lr; }
  else         { lr = lane>>2; sc = (lane&3) ^ ((lr>>1)&3); }
  size_t lsrc = (size_t)lr*K3 + sc*8;

  f32x4 acc[FM][FN];
  #pragma unroll
  for (int i=0;i<FM;++i)
    #pragma unroll
    for (int j=0;j<FN;++j) acc[i][j] = (f32x4){0,0,0,0};

  int r16 = lane & 15, g4 = lane >> 4;
  for (int k = kbeg; k < kbeg + kper; k += BK){
    for (int j = w; j < NL; j += 4){
      if (j < ALD){
        gl2lds16(A + (size_t)(m0 + j*RPL)*K3 + k + lsrc, As + j*(RPL*RB));
      } else {
        int jb = j - ALD;
        gl2lds16(B + (size_t)(n0 + jb*RPL)*K3 + k + lsrc, Bs + jb*(RPL*RB));
      }
    }
    __syncthreads();
    #pragma unroll
    for (int kh=0; kh<KH; ++kh){
      int c = kh*4 + g4;
      short8_t bf[FN];
      #pragma unroll
      for (int j2=0;j2<FN;++j2){
        int rb = wn*WCOL + j2*16 + r16;
        int pb = (BK==64) ? (c ^ (rb&7)) : (c ^ ((rb>>1)&3));
        bf[j2] = *(short8_t*)&Bs[rb*RB + pb*16];
      }
      #pragma unroll
      for (int i2=0;i2<FM;++i2){
        int ra = wm*(BM/2) + i2*16 + r16;
        int pa = (BK==64) ? (c ^ (ra&7)) : (c ^ ((ra>>1)&3));
        short8_t af = *(short8_t*)&As[ra*RB + pa*16];
        #pragma unroll
        for (int j2=0;j2<FN;++j2)
          acc[i2][j2] = __builtin_amdgcn_mfma_f32_16x16x32_bf16(af, bf[j2], acc[i2][j2], 0,0,0);
      }
    }
    __syncthreads();
  }
  #pragma unroll
  for (int i2=0;i2<FM;++i2){
    #pragma unroll
    for (int j2=0;j2<FN;++j2){
      #pragma unroll
      for (int r=0;r<4;++r){
        int m = m0 + wm*(BM/2) + i2*16 + (g4*4 + r);
        int n = n0 + wn*WCOL + j2*16 + r16;
        float v = acc[i2][j2][r];
        if (EPI==0){
          ((float*)Cv)[(size_t)blockIdx.z*((size_t)N*M) + (size_t)n*M + m] = v;
        } else if (EPI==1){
          int b = n>>10, l = n&1023;
          ((float*)Cv)[((size_t)b*M + m)*LL + l] = v;
        } else {
          float xv = v + bias[m];
          float sp = (xv > 20.f) ? xv : log1pf(__expf(xv));
          (((unsigned short*)Cv) + (size_t)dir*CStr)[(size_t)n*M + m] = f2bu(sp);
        }
      }
    }
  }
}

// -------- causal depthwise conv k4 + SiLU, bf16 transposed out; both dirs ------
__global__ __launch_bounds__(256) void dwconv_k(
    const float* __restrict__ xz, const float* __restrict__ cw0,
    const float* __restrict__ cb0, const float* __restrict__ cw1,
    const float* __restrict__ cb1, unsigned short* __restrict__ outT0)
{
  __shared__ float sx[64][73];
  int zc = blockIdx.z;
  int b = zc & 1, rev = zc >> 1;
  const float* cw = rev ? cw1 : cw0;
  const float* cb = rev ? cb1 : cb0;
  unsigned short* outT = outT0 + (size_t)rev*2097152;
  int l0 = blockIdx.x * 64;
  int d0 = blockIdx.y * 64;
  int tid = threadIdx.x;
  const float* base = xz + ((size_t)b*2048 + d0)*LL;
  for (int idx = tid; idx < 64*67; idx += 256) {
    int r = idx / 67, i = idx - r*67;
    int lp = l0 - 3 + i;
    float v = 0.f;
    if (lp >= 0) v = base[(size_t)r*LL + (rev ? (LL-1-lp) : lp)];
    sx[r][i] = v;
  }
  __syncthreads();
  int dof = tid & 63;
  int lq = tid >> 6;
  int d = d0 + dof;
  float4 w4 = *(const float4*)(cw + (size_t)d*4);
  float bv = cb[d];
  unsigned short* orow = outT + (size_t)b*LL*1024 + d;
  #pragma unroll
  for (int j=0;j<16;++j){
    int lr = lq + j*4;
    float acc = bv + w4.x*sx[dof][lr] + w4.y*sx[dof][lr+1]
                   + w4.z*sx[dof][lr+2] + w4.w*sx[dof][lr+3];
    orow[(size_t)(l0+lr)*1024] = f2bu(acc * sigmoidf_(acc));
  }
}

// ================= chunked selective scan (lane-owns-channel) =================
__global__ __launch_bounds__(256) void scan1_k(
    const unsigned short* __restrict__ de0, const unsigned short* __restrict__ de1,
    const unsigned short* __restrict__ u0, const unsigned short* __restrict__ u1,
    const float* __restrict__ xd0, const float* __restrict__ xd1,
    const float* __restrict__ al0, const float* __restrict__ al1,
    float* __restrict__ Pbuf, float* __restrict__ Sbuf)
{
  __shared__ float sBC[CS][32];
  int zc = blockIdx.z, dir = zc>>1, b = zc&1;
  const unsigned short* de = dir? de1:de0;
  const unsigned short* uT = dir? u1:u0;
  const float* xd = dir? xd1:xd0;
  const float* al = dir? al1:al0;
  int t = threadIdx.x;
  int d = blockIdx.x*128 + (t>>1);
  int sh = (t&1)*8;
  int l0 = blockIdx.y*CS;
  size_t nrow = (size_t)b*1024 + l0;
  for (int idx = t; idx < CS*32; idx += 256){
    int r = idx >> 5, c = idx & 31;
    sBC[r][c] = xd[(nrow + r)*64 + 32 + c];
  }
  __syncthreads();
  float A[8], h[8], P[8];
  #pragma unroll
  for (int j=0;j<8;++j){ A[j] = -expf(al[d*16 + sh + j]); h[j]=0.f; P[j]=1.f; }
  const unsigned short* dep = de + nrow*1024 + d;
  const unsigned short* up  = uT + nrow*1024 + d;
  for (int l=0; l<CS; ++l){
    float dv = bu2f(dep[(size_t)l*1024]);
    float uv = bu2f(up[(size_t)l*1024]);
    float du = dv*uv;
    #pragma unroll
    for (int j=0;j<8;++j){
      float a = __expf(dv*A[j]);
      h[j] = a*h[j] + du*sBC[l][sh+j];
      P[j] *= a;
    }
  }
  size_t sb = (size_t)blockIdx.y*65536 + (size_t)(zc*1024 + d)*16 + sh;
  *(float4*)&Pbuf[sb]   = make_float4(P[0],P[1],P[2],P[3]);
  *(float4*)&Pbuf[sb+4] = make_float4(P[4],P[5],P[6],P[7]);
  *(float4*)&Sbuf[sb]   = make_float4(h[0],h[1],h[2],h[3]);
  *(float4*)&Sbuf[sb+4] = make_float4(h[4],h[5],h[6],h[7]);
}

__global__ __launch_bounds__(256) void scan2_k(
    const float* __restrict__ Pbuf, const float* __restrict__ Sbuf,
    float* __restrict__ Hbuf)
{
  int seq = blockIdx.x*256 + threadIdx.x;
  float H = 0.f;
  #pragma unroll
  for (int cch=0; cch<NC; ++cch){
    Hbuf[(size_t)cch*65536 + seq] = H;
    H = Pbuf[(size_t)cch*65536 + seq]*H + Sbuf[(size_t)cch*65536 + seq];
  }
}

__global__ __launch_bounds__(256) void scan3_k(
    const unsigned short* __restrict__ de0, const unsigned short* __restrict__ de1,
    const unsigned short* __restrict__ u0, const unsigned short* __restrict__ u1,
    const float* __restrict__ xd0, const float* __restrict__ xd1,
    const float* __restrict__ al0, const float* __restrict__ al1,
    const float* __restrict__ dd0, const float* __restrict__ dd1,
    const float* __restrict__ Hbuf,
    float* __restrict__ y0, float* __restrict__ y1)
{
  __shared__ float sBC[CS][32];
  int zc = blockIdx.z, dir = zc>>1, b = zc&1;
  const unsigned short* de = dir? de1:de0;
  const unsigned short* uT = dir? u1:u0;
  const float* xd = dir? xd1:xd0;
  const float* al = dir? al1:al0;
  const float* DD = dir? dd1:dd0;
  float* y = dir? y1:y0;
  int t = threadIdx.x;
  int d = blockIdx.x*128 + (t>>1);
  int sh = (t&1)*8;
  int l0 = blockIdx.y*CS;
  size_t nrow = (size_t)b*1024 + l0;
  for (int idx = t; idx < CS*32; idx += 256){
    int r = idx >> 5, c = idx & 31;
    sBC[r][c] = xd[(nrow + r)*64 + 32 + c];
  }
  __syncthreads();
  float A[8], h[8];
  size_t sb = (size_t)blockIdx.y*65536 + (size_t)(zc*1024 + d)*16 + sh;
  float4 h03 = *(const float4*)&Hbuf[sb];
  float4 h47 = *(const float4*)&Hbuf[sb+4];
  h[0]=h03.x; h[1]=h03.y; h[2]=h03.z; h[3]=h03.w;
  h[4]=h47.x; h[5]=h47.y; h[6]=h47.z; h[7]=h47.w;
  #pragma unroll
  for (int j=0;j<8;++j) A[j] = -expf(al[d*16 + sh + j]);
  float Dd = DD[d];
  const unsigned short* dep = de + nrow*1024 + d;
  const unsigned short* up  = uT + nrow*1024 + d;
  float* yb = y + (size_t)b*LL*1024 + d;
  for (int l=0; l<CS; ++l){
    float dv = bu2f(dep[(size_t)l*1024]);
    float uv = bu2f(up[(size_t)l*1024]);
    float du = dv*uv;
    float pa = 0.f;
    #pragma unroll
    for (int j=0;j<8;++j){
      float a = __expf(dv*A[j]);
      h[j] = a*h[j] + du*sBC[l][sh+j];
      pa += h[j]*sBC[l][16+sh+j];
    }
    pa += __shfl_xor(pa, 1);
    if ((t&1)==0){
      int lo = dir ? (1023 - l0 - l) : (l0 + l);
      yb[(size_t)lo*1024] = pa + uv*Dd;
    }
  }
}

extern "C" void kernel_launch(void* const* d_in, const int* in_sizes, int n_in,
                              void* d_out, int out_size, void* d_ws, size_t ws_size,
                              hipStream_t stream)
{
  const float* x   = (const float*)d_in[0];
  const float* c1w = (const float*)d_in[1];  const float* c1b = (const float*)d_in[2];
  const float* g1g = (const float*)d_in[3];  const float* g1b = (const float*)d_in[4];
  const float* c2w = (const float*)d_in[5];  const float* c2b = (const float*)d_in[6];
  const float* g2g = (const float*)d_in[7];  const float* g2b = (const float*)d_in[8];
  const float* c3w = (const float*)d_in[9];  const float* c3b = (const float*)d_in[10];
  const float* g3g = (const float*)d_in[11]; const float* g3b = (const float*)d_in[12];
  const float* lng = (const float*)d_in[13]; const float* lnb = (const float*)d_in[14];
  const float* ipw = (const float*)d_in[15]; const float* opw = (const float*)d_in[16];
  const float* cvw[2]  = {(const float*)d_in[17], (const float*)d_in[24]};
  const float* cvb[2]  = {(const float*)d_in[18], (const float*)d_in[25]};
  const float* xpw[2]  = {(const float*)d_in[19], (const float*)d_in[26]};
  const float* dtw[2]  = {(const float*)d_in[20], (const float*)d_in[27]};
  const float* dtb[2]  = {(const float*)d_in[21], (const float*)d_in[28]};
  const float* alog[2] = {(const float*)d_in[22], (const float*)d_in[29]};
  const float* Dp[2]   = {(const float*)d_in[23], (const float*)d_in[30]};

  float* ws = (float*)d_ws;
  // ---- workspace map (floats) ----
  float* h3  = ws;                         // [0, 1048576) residual
  float* h1  = ws + 1048576;               // stem; later xdb (flat 262144)
  float* h2  = ws + 1310720;               // stem
  float* Hb  = ws + 1835008;               // scan chunk-start states (1048576)
  float* xzb = ws + 2883584;               // [.., 7077888) xz; x-halves later Pb/Sb
  unsigned short* Wb = (unsigned short*)(ws + 7077888);   // A' splits region
  unsigned short* Bsb = (unsigned short*)(ws + 8650752);  // B' splits region
  float* yy0 = ws + 11796480;
  float* yy1 = ws + 13893632;
  float* PART = ws + 15990784;             // partials (<=2097152 fl); later dl (bf16)
  unsigned short* xcv[2] = { (unsigned short*)(ws + 18087936),
                             (unsigned short*)(ws + 18087936) + 2097152 };
  // aliases
  float* xdb[2] = { ws + 1048576, ws + 1179648 };          // flat contiguous
  unsigned short* dl[2] = { (unsigned short*)PART, (unsigned short*)PART + 2097152 };
  float* Pb = ws + 2883584;                // b0 x-half (dead after dwconv)
  float* Sb = ws + 4980736;                // b1 x-half
  float* pxp = ws + 8650752;               // 16 x 131072 fp32 partials (Bsb dead here)
  unsigned short* dtB = (unsigned short*)(ws + 10747904);  // 4096x32 bf16
  unsigned short* WbXp = Wb;               // 2 x 64x1024 bf16
  unsigned short* WbDt = Wb + 131072;      // 2 x 1024x32 bf16
  float* out = (float*)d_out;

  // ================= CNN stem (split-bf16 MFMA, >=1.5 blocks/CU) =================
  ts_split3_k<<<dim3(32,24,2), 256, 0, stream>>>(x, Bsb, 768);
  wsplit3_conv_k<<<384, 256, 0, stream>>>(c1w, Wb, 128, 768);
  gemm_bf3<64,64,64,0,0><<<dim3(32,2,6), 256, 0, stream>>>(
      Wb, Bsb, nullptr, nullptr, PART, 128, 2048, 6912, 0,0,0);
  reduceK_k<1><<<1024, 256, 0, stream>>>(PART, c1b, nullptr, h1, 128, 2048, 6);
  gn_relu_k<<<64, 256, 0, stream>>>(h1, g1g, g1b, 128, 4);

  ts_split3_k<<<dim3(32,4,2), 256, 0, stream>>>(h1, Bsb, 128);
  wsplit3_conv_k<<<128, 256, 0, stream>>>(c2w, Wb, 256, 128);
  gemm_bf3<64,64,64,0,0><<<dim3(32,4,3), 256, 0, stream>>>(
      Wb, Bsb, nullptr, nullptr, PART, 256, 2048, 1152, 0,0,0);
  reduceK_k<1><<<2048, 256, 0, stream>>>(PART, c2b, nullptr, h2, 256, 2048, 3);
  gn_relu_k<<<64, 256, 0, stream>>>(h2, g2g, g2b, 256, 8);

  ts_split3_k<<<dim3(32,8,2), 256, 0, stream>>>(h2, Bsb, 256);
  wsplit3_conv_k<<<512, 256, 0, stream>>>(c3w, Wb, 512, 256);
  gemm_bf3<64,64,64,0,0><<<dim3(32,8,2), 256, 0, stream>>>(
      Wb, Bsb, nullptr, nullptr, PART, 512, 2048, 2304, 0,0,0);
  reduceK_k<1><<<4096, 256, 0, stream>>>(PART, c3b, nullptr, h3, 512, 2048, 2);
  gn_relu_k<<<64, 256, 0, stream>>>(h3, g3g, g3b, 512, 16);

  // ================= fused LN+split -> in_proj (128x64, 512 blocks) ============
  ln_split_k<<<2048, 64, 0, stream>>>(h3, lng, lnb, Bsb);
  split3_k<<<1024, 256, 0, stream>>>(ipw, Wb, 2048, 512, 512);
  gemm_bf3<128,64,64,1,0><<<dim3(32,16,1), 256, 0, stream>>>(
      Wb, Bsb, nullptr, nullptr, xzb, 2048, 2048, 1536, 0,0,0);

  // ================= per-direction conv/proj/delta (dual launches) =============
  dwconv_k<<<dim3(16,16,4), 256, 0, stream>>>(xzb, cvw[0], cvb[0], cvw[1], cvb[1], xcv[0]);
  split1x2_k<<<128, 256, 0, stream>>>(xpw[0], xpw[1], WbXp, 64, 1024, 65536);
  gemm_bf3<64,64,64,0,1><<<dim3(32,1,16), 256, 0, stream>>>(
      WbXp, xcv[0], nullptr, nullptr, pxp, 64, 2048, 1024, 65536, 2097152, 0);
  reducexp_k<<<1024, 256, 0, stream>>>(pxp, xdb[0], dtB);
  split1x2_k<<<64, 256, 0, stream>>>(dtw[0], dtw[1], WbDt, 1024, 32, 32768);
  gemm_bf3<128,64,32,2,1><<<dim3(32,8,2), 256, 0, stream>>>(
      WbDt, dtB, dtb[0], dtb[1], dl[0], 1024, 2048, 32, 32768, 65536, 2097152);

  // ================= chunked selective scan =================
  scan1_k<<<dim3(8,NC,4), 256, 0, stream>>>(
      dl[0], dl[1], xcv[0], xcv[1], xdb[0], xdb[1], alog[0], alog[1], Pb, Sb);
  scan2_k<<<256, 256, 0, stream>>>(Pb, Sb, Hb);
  scan3_k<<<dim3(8,NC,4), 256, 0, stream>>>(
      dl[0], dl[1], xcv[0], xcv[1], xdb[0], xdb[1], alog[0], alog[1],
      Dp[0], Dp[1], Hb, yy0, yy1);

  // ================= gate + out_proj (bf16 MFMA) + residual =================
  gated_split_k<<<dim3(32,32,2), 256, 0, stream>>>(yy0, yy1, xzb, Bsb);
  split1_k<<<512, 256, 0, stream>>>(opw, Wb, 512, 1024, 1024, 0);
  gemm_bf3<64,64,64,0,0><<<dim3(32,8,2), 256, 0, stream>>>(
      Wb, Bsb, nullptr, nullptr, PART, 512, 2048, 1024, 0,0,0);
  reduceK_k<2><<<4096, 256, 0, stream>>>(PART, nullptr, h3, out, 512, 2048, 2);
}